// Round 5
// baseline (6122.629 us; speedup 1.0000x reference)
//
#include <hip/hip_runtime.h>
#include <hip/hip_bf16.h>
#include <math.h>

namespace {

constexpr int kS = 1020, kD = 1024, kTPB = 17, kDH = 64;
constexpr int kVOBS = 4096, kVACT = 16;
constexpr int kBS = 4080;          // B*S
constexpr float kEPS = 1e-3f;

typedef float f32x4 __attribute__((ext_vector_type(4)));
typedef __bf16 bfx8 __attribute__((ext_vector_type(8)));
typedef unsigned short u16;
typedef u16 us8 __attribute__((ext_vector_type(8)));
typedef u16 us4 __attribute__((ext_vector_type(4)));

__device__ __forceinline__ float bf2f(u16 u) {
  union { unsigned int i; float f; } v; v.i = (unsigned int)u << 16; return v.f;
}
__device__ __forceinline__ u16 f2bf(float f) {
  union { float f; unsigned int i; } v; v.f = f;
  unsigned int r = v.i + 0x7FFFu + ((v.i >> 16) & 1u);
  return (u16)(r >> 16);
}

// ---------- embed: x[bs][c] = emb_sel[tok][c] + pos_emb[s][c] (f32)
__global__ void k_embed(const int* __restrict__ tokens, const float* __restrict__ pos_emb,
                        const float* __restrict__ emb_obs, const float* __restrict__ emb_act,
                        float* __restrict__ x) {
  int bs = blockIdx.x;
  int s = bs % kS;
  int tk = tokens[bs];
  bool obs = (s % kTPB) < (kTPB - 1);
  const float* e;
  if (obs) { int t2 = tk < kVOBS - 1 ? tk : kVOBS - 1; e = emb_obs + (size_t)t2 * kD; }
  else     { int t2 = tk < kVACT - 1 ? tk : kVACT - 1; e = emb_act + (size_t)t2 * kD; }
  int c = threadIdx.x * 4;
  float4 ev = *(const float4*)(e + c);
  float4 pv = *(const float4*)(pos_emb + (size_t)s * kD + c);
  float4 o; o.x = ev.x + pv.x; o.y = ev.y + pv.y; o.z = ev.z + pv.z; o.w = ev.w + pv.w;
  *(float4*)(x + (size_t)bs * kD + c) = o;
}

// ---------- LayerNorm: f32 in -> bf16 out. One block (256 thr = 4 waves) per row, D=1024.
__global__ void k_ln(const float* __restrict__ x, const float* __restrict__ g,
                     const float* __restrict__ b, u16* __restrict__ out) {
  int row = blockIdx.x;
  int t = threadIdx.x;
  const float* xr = x + (size_t)row * kD;
  float4 v = *(const float4*)(xr + t * 4);
  float s1 = v.x + v.y + v.z + v.w;
  float s2 = v.x * v.x + v.y * v.y + v.z * v.z + v.w * v.w;
  #pragma unroll
  for (int m = 32; m; m >>= 1) { s1 += __shfl_xor(s1, m); s2 += __shfl_xor(s2, m); }
  __shared__ float ls1[4], ls2[4];
  int w = t >> 6;
  if ((t & 63) == 0) { ls1[w] = s1; ls2[w] = s2; }
  __syncthreads();
  float S1 = ls1[0] + ls1[1] + ls1[2] + ls1[3];
  float S2 = ls2[0] + ls2[1] + ls2[2] + ls2[3];
  float mean = S1 * (1.0f / kD);
  float var = S2 * (1.0f / kD) - mean * mean;
  float rs = rsqrtf(var + kEPS);
  int c = t * 4;
  float4 gv = *(const float4*)(g + c);
  float4 bv = *(const float4*)(b + c);
  us4 o;
  o[0] = f2bf((v.x - mean) * rs * gv.x + bv.x);
  o[1] = f2bf((v.y - mean) * rs * gv.y + bv.y);
  o[2] = f2bf((v.z - mean) * rs * gv.z + bv.z);
  o[3] = f2bf((v.w - mean) * rs * gv.w + bv.w);
  *(us4*)(out + (size_t)row * kD + c) = o;
}

// ---------- transpose + f32->bf16: out[c][r] = in[r*ld + c], r<R, c<C.
// block (32,8), grid (C/32, R/32). R,C multiples of 32.
__global__ void k_transpose(const float* __restrict__ in, u16* __restrict__ out,
                            int R, int C, int ld) {
  __shared__ float tile[32][33];
  int tx = threadIdx.x, ty = threadIdx.y;
  int c0 = blockIdx.x * 32, r0 = blockIdx.y * 32;
  #pragma unroll
  for (int i = 0; i < 4; ++i)
    tile[ty + i * 8][tx] = in[(size_t)(r0 + ty + i * 8) * ld + c0 + tx];
  __syncthreads();
  #pragma unroll
  for (int i = 0; i < 4; ++i)
    out[(size_t)(c0 + ty + i * 8) * R + r0 + tx] = f2bf(tile[tx][ty + i * 8]);
}

// ---------- MFMA GEMM: out[M][ldo] = A[M][K](bf16) * Bt[N][K](bf16)^T + bias(f32)
// 128x128 tile, BK=32, 4 waves, each wave 64x64 (4x4 of 16x16x32 MFMA).
// EPI: 0 = bf16(val), 1 = bf16(relu), 2 = bf16(gelu exact),
//      3 = f32 resid + val, 4 = f32 plain store (d_out is float32!)
template <int EPI>
__global__ void __launch_bounds__(256)
k_gemm(const u16* __restrict__ A, const u16* __restrict__ Bt, const float* __restrict__ bias,
       const float* __restrict__ resid, void* __restrict__ out, int M, int N, int K, int ldo) {
  __shared__ alignas(16) u16 As[128][40]; // +8 pad: 80B row stride (2-way alias only, free)
  __shared__ alignas(16) u16 Bs[128][40];
  int tid = threadIdx.x;
  int m0 = blockIdx.x * 128, n0 = blockIdx.y * 128;
  int lane = tid & 63, wv = tid >> 6;
  int wm = wv >> 1, wn = wv & 1;
  f32x4 acc[4][4] = {};
  us8 zero8;
  #pragma unroll
  for (int z = 0; z < 8; ++z) zero8[z] = 0;
  int ko = (lane >> 4) * 8;

  for (int k0 = 0; k0 < K; k0 += 32) {
    #pragma unroll
    for (int it = 0; it < 2; ++it) {
      int idx = it * 256 + tid;   // 0..511
      int r = idx >> 2;           // 0..127
      int c8 = (idx & 3) * 8;     // 0,8,16,24
      int gr = m0 + r;
      us8 va = (gr < M) ? *(const us8*)(A + (size_t)gr * K + k0 + c8) : zero8;
      *(us8*)(&As[r][c8]) = va;
      int gn = n0 + r;
      us8 vb = *(const us8*)(Bt + (size_t)gn * K + k0 + c8); // N multiple of 128 everywhere
      *(us8*)(&Bs[r][c8]) = vb;
    }
    __syncthreads();
    bfx8 af[4], bfr[4];
    #pragma unroll
    for (int mf = 0; mf < 4; ++mf)
      af[mf] = *(const bfx8*)(&As[wm * 64 + mf * 16 + (lane & 15)][ko]);
    #pragma unroll
    for (int nf = 0; nf < 4; ++nf)
      bfr[nf] = *(const bfx8*)(&Bs[wn * 64 + nf * 16 + (lane & 15)][ko]);
    #pragma unroll
    for (int mf = 0; mf < 4; ++mf)
      #pragma unroll
      for (int nf = 0; nf < 4; ++nf)
        acc[mf][nf] = __builtin_amdgcn_mfma_f32_16x16x32_bf16(af[mf], bfr[nf], acc[mf][nf], 0, 0, 0);
    __syncthreads();
  }

  #pragma unroll
  for (int mf = 0; mf < 4; ++mf) {
    #pragma unroll
    for (int nf = 0; nf < 4; ++nf) {
      int gcol = n0 + wn * 64 + nf * 16 + (lane & 15);
      float bv = bias ? bias[gcol] : 0.0f;
      #pragma unroll
      for (int r = 0; r < 4; ++r) {
        int grow = m0 + wm * 64 + mf * 16 + (lane >> 4) * 4 + r;
        if (grow >= M) continue;
        float val = acc[mf][nf][r] + bv;
        size_t off2 = (size_t)grow * ldo + gcol;
        if (EPI == 0) {
          ((u16*)out)[off2] = f2bf(val);
        } else if (EPI == 1) {
          ((u16*)out)[off2] = f2bf(val > 0.f ? val : 0.f);
        } else if (EPI == 2) {
          ((u16*)out)[off2] = f2bf(0.5f * val * (1.f + erff(val * 0.70710678118654752440f)));
        } else if (EPI == 3) {
          ((float*)out)[off2] = resid[off2] + val;
        } else {
          ((float*)out)[off2] = val;   // EPI 4: f32 plain store (final output dtype)
        }
      }
    }
  }
}

// ---------- attention: one wave per (b,h,q-row), online softmax, f32 math on bf16 q/k/v.
__global__ void __launch_bounds__(256)
k_attn(const u16* __restrict__ q, const u16* __restrict__ k, const u16* __restrict__ v,
       u16* __restrict__ o) {
  int bh = blockIdx.x;            // 0..63
  int b = bh >> 4, hh = bh & 15;
  int w = threadIdx.x >> 6, lane = threadIdx.x & 63;
  int sq = blockIdx.y * 4 + w;    // 255*4 = 1020 rows exactly
  __shared__ float qs[4][64];
  size_t rowoff = ((size_t)(b * kS + sq)) * kD + hh * kDH;
  qs[w][lane] = 0.125f * bf2f(q[rowoff + lane]); // fold 1/sqrt(64) into q
  __syncthreads();
  float m = -1e30f, lsum = 0.f, oacc = 0.f;
  int ntiles = (sq >> 6) + 1;
  for (int kt = 0; kt < ntiles; ++kt) {
    int kk = kt * 64 + lane;
    float s = -1e30f;
    if (kk <= sq) {
      const u16* kr = k + ((size_t)(b * kS + kk)) * kD + hh * kDH;
      float a = 0.f;
      #pragma unroll
      for (int j8 = 0; j8 < 8; ++j8) {
        us8 kv = *(const us8*)(kr + j8 * 8);
        const float* qp = &qs[w][j8 * 8];
        #pragma unroll
        for (int jj = 0; jj < 8; ++jj) a += qp[jj] * bf2f(kv[jj]);
      }
      s = a;
    }
    float tm = s;
    #pragma unroll
    for (int msk = 32; msk; msk >>= 1) tm = fmaxf(tm, __shfl_xor(tm, msk));
    float mnew = fmaxf(m, tm);
    float alpha = expf(m - mnew);          // m=-1e30 first tile -> alpha=0
    float p = (kk <= sq) ? expf(s - mnew) : 0.f;
    float ps = p;
    #pragma unroll
    for (int msk = 32; msk; msk >>= 1) ps += __shfl_xor(ps, msk);
    lsum = lsum * alpha + ps;
    oacc *= alpha;
    int lmax = sq - kt * 64; if (lmax > 63) lmax = 63;
    const u16* vr = v + ((size_t)(b * kS + kt * 64)) * kD + hh * kDH + lane;
    for (int l = 0; l <= lmax; ++l)
      oacc += __shfl(p, l) * bf2f(vr[(size_t)l * kD]);
    m = mnew;
  }
  o[rowoff + lane] = f2bf(oacc / lsum);
}

// ---------- gathers (bf16 row copies)
__global__ void k_gather_obs(const u16* __restrict__ xf, u16* __restrict__ xo) {
  int r = blockIdx.x;              // 0..3839
  int b = r / 960, rr = r % 960;
  int j = rr & 15, blk = rr >> 4;
  int s = blk * kTPB + j + (j == 15 ? 1 : 0); // residues 0..14,16
  const unsigned int* src = (const unsigned int*)(xf + ((size_t)(b * kS + s)) * kD);
  unsigned int* dst = (unsigned int*)(xo + (size_t)r * kD);
  dst[threadIdx.x] = src[threadIdx.x];
  dst[threadIdx.x + 256] = src[threadIdx.x + 256];
}
__global__ void k_gather_act(const u16* __restrict__ xf, u16* __restrict__ xe) {
  int r = blockIdx.x;              // 0..239
  int b = r / 60, rr = r % 60;
  int s = rr * kTPB + (kTPB - 1);
  const unsigned int* src = (const unsigned int*)(xf + ((size_t)(b * kS + s)) * kD);
  unsigned int* dst = (unsigned int*)(xe + (size_t)r * kD);
  dst[threadIdx.x] = src[threadIdx.x];
  dst[threadIdx.x + 256] = src[threadIdx.x + 256];
}

// ---------- ends head: out[r][c] = sum_j t2[r][j]*he2[j][c] + be2[c], c in {0,1} (f32 out)
__global__ void k_ends(const u16* __restrict__ t2, const float* __restrict__ he2,
                       const float* __restrict__ be2, float* __restrict__ out) {
  int r = blockIdx.x; // 240
  int t = threadIdx.x;
  float p0 = 0.f, p1 = 0.f;
  for (int j = t; j < kD; j += 256) {
    float xv = bf2f(t2[(size_t)r * kD + j]);
    p0 += xv * he2[j * 2];
    p1 += xv * he2[j * 2 + 1];
  }
  #pragma unroll
  for (int msk = 32; msk; msk >>= 1) { p0 += __shfl_xor(p0, msk); p1 += __shfl_xor(p1, msk); }
  __shared__ float l0[4], l1[4];
  int w = t >> 6;
  if ((t & 63) == 0) { l0[w] = p0; l1[w] = p1; }
  __syncthreads();
  if (t == 0) {
    out[r * 2 + 0] = l0[0] + l0[1] + l0[2] + l0[3] + be2[0];
    out[r * 2 + 1] = l1[0] + l1[1] + l1[2] + l1[3] + be2[1];
  }
}

} // namespace

extern "C" void kernel_launch(void* const* d_in, const int* in_sizes, int n_in,
                              void* d_out, int out_size, void* d_ws, size_t ws_size,
                              hipStream_t stream) {
  // Inputs are float32 (per reference setup_inputs); OUTPUT is float32 too.
  const int*   tokens  = (const int*)  d_in[0];
  const float* pos_emb = (const float*)d_in[1];
  const float* emb_obs = (const float*)d_in[2];
  const float* emb_act = (const float*)d_in[3];
  const float* ln1_g = (const float*)d_in[4];
  const float* ln1_b = (const float*)d_in[5];
  const float* wq = (const float*)d_in[6];
  const float* bq = (const float*)d_in[7];
  const float* wk = (const float*)d_in[8];
  const float* bk = (const float*)d_in[9];
  const float* wv = (const float*)d_in[10];
  const float* bv = (const float*)d_in[11];
  const float* wo = (const float*)d_in[12];
  const float* bo = (const float*)d_in[13];
  const float* ln2_g = (const float*)d_in[14];
  const float* ln2_b = (const float*)d_in[15];
  const float* w1 = (const float*)d_in[16];
  const float* b1 = (const float*)d_in[17];
  const float* w2 = (const float*)d_in[18];
  const float* b2 = (const float*)d_in[19];
  const float* lnf_g = (const float*)d_in[20];
  const float* lnf_b = (const float*)d_in[21];
  const float* ho1 = (const float*)d_in[22];
  const float* bo1 = (const float*)d_in[23];
  const float* ho2 = (const float*)d_in[24];
  const float* bo2 = (const float*)d_in[25];
  const float* he1 = (const float*)d_in[26];
  const float* be1 = (const float*)d_in[27];
  const float* he2 = (const float*)d_in[28];
  const float* be2 = (const float*)d_in[29];
  (void)in_sizes; (void)n_in; (void)out_size; (void)ws_size;

  // ---- workspace layout: 60.5 MB (identical to rounds 2-3).
  char* ws = (char*)d_ws;
  size_t off = 0;
  auto alloc = [&](size_t bytes) -> char* {
    char* p = ws + off; off += (bytes + 255) & ~(size_t)255; return p;
  };
  u16*   wT = (u16*)alloc((size_t)1024 * 1024 * 2);       // 2 MB, reused per weight chunk
  float* x  = (float*)alloc((size_t)kBS * kD * 4);        // 16.71 MB f32 residual
  u16*   h  = (u16*)alloc((size_t)kBS * kD * 2);          // 8.36 MB LN output
  const size_t slotB = (size_t)kBS * kD * 2;              // 8,355,840 B
  char* s0 = alloc(slotB);  // q   | mid (FFN) | xf (post-loop)
  char* s1 = alloc(slotB);  // k   | xo
  char* s2 = alloc(slotB);  // v   | t1
  char* s3 = alloc(slotB);  // o   | xe + t2
  u16* qb = (u16*)s0; u16* kb = (u16*)s1; u16* vb = (u16*)s2; u16* ob = (u16*)s3;
  u16* mid = (u16*)s0;                      // q dead by FFN time
  u16* xf = (u16*)s0;                       // layer activations dead after loop
  u16* xo = (u16*)s1;
  u16* t1 = (u16*)s2;
  u16* xe = (u16*)s3;
  u16* t2 = (u16*)(s3 + (size_t)240 * kD * 2 + 256);

  dim3 tb(32, 8);
  dim3 tg(32, 32);                 // transpose grid for 1024x1024 chunks
  dim3 gg(32, 8);                  // gemm grid M=4080(32), N=1024(8)
  k_embed<<<kBS, 256, 0, stream>>>(tokens, pos_emb, emb_obs, emb_act, x);

  for (int i = 0; i < 4; ++i) {
    const size_t wOff = (size_t)i * kD * kD;
    k_ln<<<kBS, 256, 0, stream>>>(x, ln1_g + i * kD, ln1_b + i * kD, h);

    k_transpose<<<tg, tb, 0, stream>>>(wq + wOff, wT, 1024, 1024, 1024);
    k_gemm<0><<<gg, 256, 0, stream>>>(h, wT, bq + i * kD, nullptr, qb, kBS, 1024, 1024, 1024);
    k_transpose<<<tg, tb, 0, stream>>>(wk + wOff, wT, 1024, 1024, 1024);
    k_gemm<0><<<gg, 256, 0, stream>>>(h, wT, bk + i * kD, nullptr, kb, kBS, 1024, 1024, 1024);
    k_transpose<<<tg, tb, 0, stream>>>(wv + wOff, wT, 1024, 1024, 1024);
    k_gemm<0><<<gg, 256, 0, stream>>>(h, wT, bv + i * kD, nullptr, vb, kBS, 1024, 1024, 1024);

    k_attn<<<dim3(64, 255), 256, 0, stream>>>(qb, kb, vb, ob);

    k_transpose<<<tg, tb, 0, stream>>>(wo + wOff, wT, 1024, 1024, 1024);
    k_gemm<3><<<gg, 256, 0, stream>>>(ob, wT, bo + i * kD, x, x, kBS, 1024, 1024, 1024);

    k_ln<<<kBS, 256, 0, stream>>>(x, ln2_g + i * kD, ln2_b + i * kD, h);

    // FFN in 4 N-chunks of 1024: mid = gelu(h @ w1[:, c*1024..] + b1_c);
    // x += mid @ w2[c*1024.., :] (+ b2 on chunk 0 only)
    for (int c = 0; c < 4; ++c) {
      k_transpose<<<tg, tb, 0, stream>>>(w1 + (size_t)i * kD * 4096 + c * 1024, wT,
                                         1024, 1024, 4096);
      k_gemm<2><<<gg, 256, 0, stream>>>(h, wT, b1 + i * 4096 + c * 1024, nullptr, mid,
                                        kBS, 1024, 1024, 1024);
      k_transpose<<<tg, tb, 0, stream>>>(w2 + (size_t)i * 4096 * kD + (size_t)c * 1024 * 1024,
                                         wT, 1024, 1024, 1024);
      k_gemm<3><<<gg, 256, 0, stream>>>(mid, wT, (c == 0) ? (b2 + i * kD) : nullptr, x, x,
                                        kBS, 1024, 1024, 1024);
    }
  }

  k_ln<<<kBS, 256, 0, stream>>>(x, lnf_g, lnf_b, xf);
  k_gather_obs<<<3840, 256, 0, stream>>>(xf, xo);
  k_gather_act<<<240, 256, 0, stream>>>(xf, xe);

  // obs head: t1 = relu(xo@ho1+bo1) [bf16]; d_out[:3840*4096] = t1@ho2 + bo2 [f32]
  k_transpose<<<tg, tb, 0, stream>>>(ho1, wT, 1024, 1024, 1024);
  k_gemm<1><<<dim3(30, 8), 256, 0, stream>>>(xo, wT, bo1, nullptr, t1, 3840, 1024, 1024, 1024);
  for (int c = 0; c < 4; ++c) {
    k_transpose<<<tg, tb, 0, stream>>>(ho2 + c * 1024, wT, 1024, 1024, 4096);
    k_gemm<4><<<dim3(30, 8), 256, 0, stream>>>(t1, wT, bo2 + c * 1024, nullptr,
                                               (float*)d_out + c * 1024, 3840, 1024, 1024, 4096);
  }
  // ends head: f32 out at element offset 3840*4096
  k_transpose<<<tg, tb, 0, stream>>>(he1, wT, 1024, 1024, 1024);
  k_gemm<1><<<dim3(2, 8), 256, 0, stream>>>(xe, wT, be1, nullptr, t2, 240, 1024, 1024, 1024);
  k_ends<<<240, 256, 0, stream>>>(t2, he2, be2, (float*)d_out + (size_t)3840 * 4096);
}

// Round 6
// 2724.069 us; speedup vs baseline: 2.2476x; 2.2476x over previous
//
#include <hip/hip_runtime.h>
#include <hip/hip_bf16.h>
#include <math.h>

namespace {

constexpr int kS = 1020, kD = 1024, kTPB = 17, kDH = 64;
constexpr int kVOBS = 4096, kVACT = 16;
constexpr int kBS = 4080;          // B*S
constexpr float kEPS = 1e-3f;

typedef float f32x4 __attribute__((ext_vector_type(4)));
typedef __bf16 bfx8 __attribute__((ext_vector_type(8)));
typedef unsigned short u16;
typedef u16 us8 __attribute__((ext_vector_type(8)));
typedef u16 us4 __attribute__((ext_vector_type(4)));

__device__ __forceinline__ float bf2f(u16 u) {
  union { unsigned int i; float f; } v; v.i = (unsigned int)u << 16; return v.f;
}
__device__ __forceinline__ u16 f2bf(float f) {
  union { float f; unsigned int i; } v; v.f = f;
  unsigned int r = v.i + 0x7FFFu + ((v.i >> 16) & 1u);
  return (u16)(r >> 16);
}

// ---------- embed: x[bs][c] = emb_sel[tok][c] + pos_emb[s][c] (f32)
__global__ void k_embed(const int* __restrict__ tokens, const float* __restrict__ pos_emb,
                        const float* __restrict__ emb_obs, const float* __restrict__ emb_act,
                        float* __restrict__ x) {
  int bs = blockIdx.x;
  int s = bs % kS;
  int tk = tokens[bs];
  bool obs = (s % kTPB) < (kTPB - 1);
  const float* e;
  if (obs) { int t2 = tk < kVOBS - 1 ? tk : kVOBS - 1; e = emb_obs + (size_t)t2 * kD; }
  else     { int t2 = tk < kVACT - 1 ? tk : kVACT - 1; e = emb_act + (size_t)t2 * kD; }
  int c = threadIdx.x * 4;
  float4 ev = *(const float4*)(e + c);
  float4 pv = *(const float4*)(pos_emb + (size_t)s * kD + c);
  float4 o; o.x = ev.x + pv.x; o.y = ev.y + pv.y; o.z = ev.z + pv.z; o.w = ev.w + pv.w;
  *(float4*)(x + (size_t)bs * kD + c) = o;
}

// ---------- LayerNorm: f32 in -> bf16 out. One block (256 thr = 4 waves) per row, D=1024.
__global__ void k_ln(const float* __restrict__ x, const float* __restrict__ g,
                     const float* __restrict__ b, u16* __restrict__ out) {
  int row = blockIdx.x;
  int t = threadIdx.x;
  const float* xr = x + (size_t)row * kD;
  float4 v = *(const float4*)(xr + t * 4);
  float s1 = v.x + v.y + v.z + v.w;
  float s2 = v.x * v.x + v.y * v.y + v.z * v.z + v.w * v.w;
  #pragma unroll
  for (int m = 32; m; m >>= 1) { s1 += __shfl_xor(s1, m); s2 += __shfl_xor(s2, m); }
  __shared__ float ls1[4], ls2[4];
  int w = t >> 6;
  if ((t & 63) == 0) { ls1[w] = s1; ls2[w] = s2; }
  __syncthreads();
  float S1 = ls1[0] + ls1[1] + ls1[2] + ls1[3];
  float S2 = ls2[0] + ls2[1] + ls2[2] + ls2[3];
  float mean = S1 * (1.0f / kD);
  float var = S2 * (1.0f / kD) - mean * mean;
  float rs = rsqrtf(var + kEPS);
  int c = t * 4;
  float4 gv = *(const float4*)(g + c);
  float4 bv = *(const float4*)(b + c);
  us4 o;
  o[0] = f2bf((v.x - mean) * rs * gv.x + bv.x);
  o[1] = f2bf((v.y - mean) * rs * gv.y + bv.y);
  o[2] = f2bf((v.z - mean) * rs * gv.z + bv.z);
  o[3] = f2bf((v.w - mean) * rs * gv.w + bv.w);
  *(us4*)(out + (size_t)row * kD + c) = o;
}

// ---------- transpose + f32->bf16: out[c][r] = in[r*ld + c], r<R, c<C.
__global__ void k_transpose(const float* __restrict__ in, u16* __restrict__ out,
                            int R, int C, int ld) {
  __shared__ float tile[32][33];
  int tx = threadIdx.x, ty = threadIdx.y;
  int c0 = blockIdx.x * 32, r0 = blockIdx.y * 32;
  #pragma unroll
  for (int i = 0; i < 4; ++i)
    tile[ty + i * 8][tx] = in[(size_t)(r0 + ty + i * 8) * ld + c0 + tx];
  __syncthreads();
  #pragma unroll
  for (int i = 0; i < 4; ++i)
    out[(size_t)(c0 + ty + i * 8) * R + r0 + tx] = f2bf(tile[tx][ty + i * 8]);
}

// ---------- MFMA GEMM: out[M][ldo] = A[M][K](bf16) * Bt[N][K](bf16)^T + bias(f32)
// EPI: 0 = bf16(val), 1 = bf16(relu), 2 = bf16(gelu exact),
//      3 = f32 resid + val, 4 = f32 plain store
template <int EPI>
__global__ void __launch_bounds__(256)
k_gemm(const u16* __restrict__ A, const u16* __restrict__ Bt, const float* __restrict__ bias,
       const float* __restrict__ resid, void* __restrict__ out, int M, int N, int K, int ldo) {
  __shared__ alignas(16) u16 As[128][40];
  __shared__ alignas(16) u16 Bs[128][40];
  int tid = threadIdx.x;
  int m0 = blockIdx.x * 128, n0 = blockIdx.y * 128;
  int lane = tid & 63, wv = tid >> 6;
  int wm = wv >> 1, wn = wv & 1;
  f32x4 acc[4][4] = {};
  us8 zero8;
  #pragma unroll
  for (int z = 0; z < 8; ++z) zero8[z] = 0;
  int ko = (lane >> 4) * 8;

  for (int k0 = 0; k0 < K; k0 += 32) {
    #pragma unroll
    for (int it = 0; it < 2; ++it) {
      int idx = it * 256 + tid;
      int r = idx >> 2;
      int c8 = (idx & 3) * 8;
      int gr = m0 + r;
      us8 va = (gr < M) ? *(const us8*)(A + (size_t)gr * K + k0 + c8) : zero8;
      *(us8*)(&As[r][c8]) = va;
      int gn = n0 + r;
      us8 vb = *(const us8*)(Bt + (size_t)gn * K + k0 + c8);
      *(us8*)(&Bs[r][c8]) = vb;
    }
    __syncthreads();
    bfx8 af[4], bfr[4];
    #pragma unroll
    for (int mf = 0; mf < 4; ++mf)
      af[mf] = *(const bfx8*)(&As[wm * 64 + mf * 16 + (lane & 15)][ko]);
    #pragma unroll
    for (int nf = 0; nf < 4; ++nf)
      bfr[nf] = *(const bfx8*)(&Bs[wn * 64 + nf * 16 + (lane & 15)][ko]);
    #pragma unroll
    for (int mf = 0; mf < 4; ++mf)
      #pragma unroll
      for (int nf = 0; nf < 4; ++nf)
        acc[mf][nf] = __builtin_amdgcn_mfma_f32_16x16x32_bf16(af[mf], bfr[nf], acc[mf][nf], 0, 0, 0);
    __syncthreads();
  }

  #pragma unroll
  for (int mf = 0; mf < 4; ++mf) {
    #pragma unroll
    for (int nf = 0; nf < 4; ++nf) {
      int gcol = n0 + wn * 64 + nf * 16 + (lane & 15);
      float bv = bias ? bias[gcol] : 0.0f;
      #pragma unroll
      for (int r = 0; r < 4; ++r) {
        int grow = m0 + wm * 64 + mf * 16 + (lane >> 4) * 4 + r;
        if (grow >= M) continue;
        float val = acc[mf][nf][r] + bv;
        size_t off2 = (size_t)grow * ldo + gcol;
        if (EPI == 0) {
          ((u16*)out)[off2] = f2bf(val);
        } else if (EPI == 1) {
          ((u16*)out)[off2] = f2bf(val > 0.f ? val : 0.f);
        } else if (EPI == 2) {
          ((u16*)out)[off2] = f2bf(0.5f * val * (1.f + erff(val * 0.70710678118654752440f)));
        } else if (EPI == 3) {
          ((float*)out)[off2] = resid[off2] + val;
        } else {
          ((float*)out)[off2] = val;
        }
      }
    }
  }
}

// ---------- MFMA flash attention (swapped-operand, 16x16x32 bf16).
// Grid: (16 q-blocks, 64 b*h). Block = 256 thr = 4 waves; wave w owns q rows
// q0 = 64*blockIdx.x + 16w .. +15. K-tile = 64 keys staged in LDS:
//   Kl[64][64] row-major, Vt[64][64] = V^T row-major, both XOR-swizzled.
// S^T[k][q] = mfma(K_frag, Q_frag); online softmax per q-column (lane&15);
// PV uses k-slot remap so P^T comes from own registers (no shuffles):
//   slot s=8g+j  <->  key 32h + 16*(j>>2) + 4g + (j&3).
__device__ __forceinline__ int swz(int row, int colu16) {
  // u16-index swizzle: spreads both (row varies, col fixed) read patterns.
  return (row * 64 + colu16) ^ ((row & 7) << 3) ^ ((row & 24) << 1);
}

__global__ void __launch_bounds__(256)
k_attn(const u16* __restrict__ q, const u16* __restrict__ k, const u16* __restrict__ v,
       u16* __restrict__ o) {
  __shared__ u16 Kl[64 * 64];
  __shared__ u16 Vt[64 * 64];
  const int qb = blockIdx.x * 64;      // q-block base
  const int bh = blockIdx.y;           // 0..63
  const int b = bh >> 4, hh = bh & 15;
  const int tid = threadIdx.x;
  const int lane = tid & 63, w = tid >> 6;
  const int g = lane >> 4, c = lane & 15;
  const int q0 = qb + w * 16;
  const size_t base = (size_t)(b * kS) * kD + hh * kDH;

  // Q fragments (B operand): qf[dh][j] = Q[q0+c][32*dh + 8g + j]
  bfx8 qf0, qf1;
  {
    int qr = q0 + c; if (qr >= kS) qr = kS - 1;    // clamp tail (rows 1020..1023)
    const u16* qp = q + base + (size_t)qr * kD + g * 8;
    qf0 = *(const bfx8*)(qp);
    qf1 = *(const bfx8*)(qp + 32);
  }

  float mst = -1e30f, lsum = 0.f;
  f32x4 ot[4] = {};   // O^T acc: ot[db][r] = O^T[d=16db+4g+r][q=c]

  const int ntiles = blockIdx.x + 1;
  for (int t = 0; t < ntiles; ++t) {
    const int kt = t * 64;
    // ---- stage K and V^T (coalesced global us8 reads; swizzled LDS)
    {
      int kr = tid >> 2, ds2 = (tid & 3) * 16;
      int kg = kt + kr; if (kg >= kS) kg = kS - 1;
      const u16* kp = k + base + (size_t)kg * kD + ds2;
      us8 a0 = *(const us8*)(kp);
      us8 a1 = *(const us8*)(kp + 8);
      *(us8*)(&Kl[swz(kr, ds2)]) = a0;
      *(us8*)(&Kl[swz(kr, ds2 + 8)]) = a1;
      const u16* vp = v + base + (size_t)kg * kD + ds2;
      us8 b0 = *(const us8*)(vp);
      us8 b1 = *(const us8*)(vp + 8);
      #pragma unroll
      for (int i2 = 0; i2 < 8; ++i2) Vt[swz(ds2 + i2, kr)] = b0[i2];
      #pragma unroll
      for (int i2 = 0; i2 < 8; ++i2) Vt[swz(ds2 + 8 + i2, kr)] = b1[i2];
    }
    __syncthreads();

    // ---- S^T = K·Q^T : 4 blocks of 16 keys, contraction d=64 (2 mfma each)
    f32x4 s[4];
    #pragma unroll
    for (int kb = 0; kb < 4; ++kb) {
      bfx8 kf0 = *(const bfx8*)(&Kl[swz(kb * 16 + c, g * 8)]);
      bfx8 kf1 = *(const bfx8*)(&Kl[swz(kb * 16 + c, g * 8 + 32)]);
      f32x4 acc = {};
      acc = __builtin_amdgcn_mfma_f32_16x16x32_bf16(kf0, qf0, acc, 0, 0, 0);
      acc = __builtin_amdgcn_mfma_f32_16x16x32_bf16(kf1, qf1, acc, 0, 0, 0);
      s[kb] = acc;
    }

    // ---- scale + causal mask + online softmax (per q-column = lane&15)
    const int qg = q0 + c;
    const bool diag = (kt + 63 > q0);
    float p[4][4];
    float tmax = -1e30f;
    #pragma unroll
    for (int kb = 0; kb < 4; ++kb)
      #pragma unroll
      for (int r = 0; r < 4; ++r) {
        float val = s[kb][r] * 0.125f;
        if (diag && (kt + kb * 16 + g * 4 + r > qg)) val = -1e30f;
        p[kb][r] = val;
        tmax = fmaxf(tmax, val);
      }
    tmax = fmaxf(tmax, __shfl_xor(tmax, 16));
    tmax = fmaxf(tmax, __shfl_xor(tmax, 32));
    float mnew = fmaxf(mst, tmax);
    float alpha = __expf(mst - mnew);
    float psum = 0.f;
    #pragma unroll
    for (int kb = 0; kb < 4; ++kb)
      #pragma unroll
      for (int r = 0; r < 4; ++r) {
        float e = __expf(p[kb][r] - mnew);
        p[kb][r] = e;
        psum += e;
      }
    psum += __shfl_xor(psum, 16);
    psum += __shfl_xor(psum, 32);
    lsum = lsum * alpha + psum;
    mst = mnew;
    #pragma unroll
    for (int db = 0; db < 4; ++db) {
      ot[db][0] *= alpha; ot[db][1] *= alpha;
      ot[db][2] *= alpha; ot[db][3] *= alpha;
    }

    // ---- PV: O^T += V^T · P^T  (k-slot remap; P from own regs, V^T via 2x b64)
    #pragma unroll
    for (int h = 0; h < 2; ++h) {
      bfx8 pf;
      #pragma unroll
      for (int j = 0; j < 8; ++j)
        pf[j] = (__bf16)p[2 * h + (j >> 2)][j & 3];
      #pragma unroll
      for (int db = 0; db < 4; ++db) {
        us4 lo = *(const us4*)(&Vt[swz(16 * db + c, 32 * h + 4 * g)]);
        us4 hi = *(const us4*)(&Vt[swz(16 * db + c, 32 * h + 16 + 4 * g)]);
        union { us8 u; bfx8 bf; } cv;
        cv.u[0] = lo[0]; cv.u[1] = lo[1]; cv.u[2] = lo[2]; cv.u[3] = lo[3];
        cv.u[4] = hi[0]; cv.u[5] = hi[1]; cv.u[6] = hi[2]; cv.u[7] = hi[3];
        ot[db] = __builtin_amdgcn_mfma_f32_16x16x32_bf16(cv.bf, pf, ot[db], 0, 0, 0);
      }
    }
    __syncthreads();
  }

  // ---- epilogue: normalize and store O rows (skip nonexistent tail rows)
  if (q0 + c < kS) {
    float inv = 1.0f / lsum;
    u16* op = o + base + (size_t)(q0 + c) * kD;
    #pragma unroll
    for (int db = 0; db < 4; ++db)
      #pragma unroll
      for (int r = 0; r < 4; ++r)
        op[16 * db + 4 * g + r] = f2bf(ot[db][r] * inv);
  }
}

// ---------- gathers (bf16 row copies)
__global__ void k_gather_obs(const u16* __restrict__ xf, u16* __restrict__ xo) {
  int r = blockIdx.x;
  int b = r / 960, rr = r % 960;
  int j = rr & 15, blk = rr >> 4;
  int s = blk * kTPB + j + (j == 15 ? 1 : 0);
  const unsigned int* src = (const unsigned int*)(xf + ((size_t)(b * kS + s)) * kD);
  unsigned int* dst = (unsigned int*)(xo + (size_t)r * kD);
  dst[threadIdx.x] = src[threadIdx.x];
  dst[threadIdx.x + 256] = src[threadIdx.x + 256];
}
__global__ void k_gather_act(const u16* __restrict__ xf, u16* __restrict__ xe) {
  int r = blockIdx.x;
  int b = r / 60, rr = r % 60;
  int s = rr * kTPB + (kTPB - 1);
  const unsigned int* src = (const unsigned int*)(xf + ((size_t)(b * kS + s)) * kD);
  unsigned int* dst = (unsigned int*)(xe + (size_t)r * kD);
  dst[threadIdx.x] = src[threadIdx.x];
  dst[threadIdx.x + 256] = src[threadIdx.x + 256];
}

// ---------- ends head: out[r][c] = sum_j t2[r][j]*he2[j][c] + be2[c] (f32 out)
__global__ void k_ends(const u16* __restrict__ t2, const float* __restrict__ he2,
                       const float* __restrict__ be2, float* __restrict__ out) {
  int r = blockIdx.x;
  int t = threadIdx.x;
  float p0 = 0.f, p1 = 0.f;
  for (int j = t; j < kD; j += 256) {
    float xv = bf2f(t2[(size_t)r * kD + j]);
    p0 += xv * he2[j * 2];
    p1 += xv * he2[j * 2 + 1];
  }
  #pragma unroll
  for (int msk = 32; msk; msk >>= 1) { p0 += __shfl_xor(p0, msk); p1 += __shfl_xor(p1, msk); }
  __shared__ float l0[4], l1[4];
  int w = t >> 6;
  if ((t & 63) == 0) { l0[w] = p0; l1[w] = p1; }
  __syncthreads();
  if (t == 0) {
    out[r * 2 + 0] = l0[0] + l0[1] + l0[2] + l0[3] + be2[0];
    out[r * 2 + 1] = l1[0] + l1[1] + l1[2] + l1[3] + be2[1];
  }
}

} // namespace

extern "C" void kernel_launch(void* const* d_in, const int* in_sizes, int n_in,
                              void* d_out, int out_size, void* d_ws, size_t ws_size,
                              hipStream_t stream) {
  const int*   tokens  = (const int*)  d_in[0];
  const float* pos_emb = (const float*)d_in[1];
  const float* emb_obs = (const float*)d_in[2];
  const float* emb_act = (const float*)d_in[3];
  const float* ln1_g = (const float*)d_in[4];
  const float* ln1_b = (const float*)d_in[5];
  const float* wq = (const float*)d_in[6];
  const float* bq = (const float*)d_in[7];
  const float* wk = (const float*)d_in[8];
  const float* bk = (const float*)d_in[9];
  const float* wv = (const float*)d_in[10];
  const float* bv = (const float*)d_in[11];
  const float* wo = (const float*)d_in[12];
  const float* bo = (const float*)d_in[13];
  const float* ln2_g = (const float*)d_in[14];
  const float* ln2_b = (const float*)d_in[15];
  const float* w1 = (const float*)d_in[16];
  const float* b1 = (const float*)d_in[17];
  const float* w2 = (const float*)d_in[18];
  const float* b2 = (const float*)d_in[19];
  const float* lnf_g = (const float*)d_in[20];
  const float* lnf_b = (const float*)d_in[21];
  const float* ho1 = (const float*)d_in[22];
  const float* bo1 = (const float*)d_in[23];
  const float* ho2 = (const float*)d_in[24];
  const float* bo2 = (const float*)d_in[25];
  const float* he1 = (const float*)d_in[26];
  const float* be1 = (const float*)d_in[27];
  const float* he2 = (const float*)d_in[28];
  const float* be2 = (const float*)d_in[29];
  (void)in_sizes; (void)n_in; (void)out_size; (void)ws_size;

  // ---- workspace layout: 60.5 MB (unchanged from round 5).
  char* ws = (char*)d_ws;
  size_t off = 0;
  auto alloc = [&](size_t bytes) -> char* {
    char* p = ws + off; off += (bytes + 255) & ~(size_t)255; return p;
  };
  u16*   wT = (u16*)alloc((size_t)1024 * 1024 * 2);
  float* x  = (float*)alloc((size_t)kBS * kD * 4);
  u16*   h  = (u16*)alloc((size_t)kBS * kD * 2);
  const size_t slotB = (size_t)kBS * kD * 2;
  char* s0 = alloc(slotB);  // q   | mid (FFN) | xf (post-loop)
  char* s1 = alloc(slotB);  // k   | xo
  char* s2 = alloc(slotB);  // v   | t1
  char* s3 = alloc(slotB);  // o   | xe + t2
  u16* qb = (u16*)s0; u16* kb = (u16*)s1; u16* vb = (u16*)s2; u16* ob = (u16*)s3;
  u16* mid = (u16*)s0;
  u16* xf = (u16*)s0;
  u16* xo = (u16*)s1;
  u16* t1 = (u16*)s2;
  u16* xe = (u16*)s3;
  u16* t2 = (u16*)(s3 + (size_t)240 * kD * 2 + 256);

  dim3 tb(32, 8);
  dim3 tg(32, 32);
  dim3 gg(32, 8);
  k_embed<<<kBS, 256, 0, stream>>>(tokens, pos_emb, emb_obs, emb_act, x);

  for (int i = 0; i < 4; ++i) {
    const size_t wOff = (size_t)i * kD * kD;
    k_ln<<<kBS, 256, 0, stream>>>(x, ln1_g + i * kD, ln1_b + i * kD, h);

    k_transpose<<<tg, tb, 0, stream>>>(wq + wOff, wT, 1024, 1024, 1024);
    k_gemm<0><<<gg, 256, 0, stream>>>(h, wT, bq + i * kD, nullptr, qb, kBS, 1024, 1024, 1024);
    k_transpose<<<tg, tb, 0, stream>>>(wk + wOff, wT, 1024, 1024, 1024);
    k_gemm<0><<<gg, 256, 0, stream>>>(h, wT, bk + i * kD, nullptr, kb, kBS, 1024, 1024, 1024);
    k_transpose<<<tg, tb, 0, stream>>>(wv + wOff, wT, 1024, 1024, 1024);
    k_gemm<0><<<gg, 256, 0, stream>>>(h, wT, bv + i * kD, nullptr, vb, kBS, 1024, 1024, 1024);

    k_attn<<<dim3(16, 64), 256, 0, stream>>>(qb, kb, vb, ob);

    k_transpose<<<tg, tb, 0, stream>>>(wo + wOff, wT, 1024, 1024, 1024);
    k_gemm<3><<<gg, 256, 0, stream>>>(ob, wT, bo + i * kD, x, x, kBS, 1024, 1024, 1024);

    k_ln<<<kBS, 256, 0, stream>>>(x, ln2_g + i * kD, ln2_b + i * kD, h);

    for (int c = 0; c < 4; ++c) {
      k_transpose<<<tg, tb, 0, stream>>>(w1 + (size_t)i * kD * 4096 + c * 1024, wT,
                                         1024, 1024, 4096);
      k_gemm<2><<<gg, 256, 0, stream>>>(h, wT, b1 + i * 4096 + c * 1024, nullptr, mid,
                                        kBS, 1024, 1024, 1024);
      k_transpose<<<tg, tb, 0, stream>>>(w2 + (size_t)i * 4096 * kD + (size_t)c * 1024 * 1024,
                                         wT, 1024, 1024, 1024);
      k_gemm<3><<<gg, 256, 0, stream>>>(mid, wT, (c == 0) ? (b2 + i * kD) : nullptr, x, x,
                                        kBS, 1024, 1024, 1024);
    }
  }

  k_ln<<<kBS, 256, 0, stream>>>(x, lnf_g, lnf_b, xf);
  k_gather_obs<<<3840, 256, 0, stream>>>(xf, xo);
  k_gather_act<<<240, 256, 0, stream>>>(xf, xe);

  // obs head
  k_transpose<<<tg, tb, 0, stream>>>(ho1, wT, 1024, 1024, 1024);
  k_gemm<1><<<dim3(30, 8), 256, 0, stream>>>(xo, wT, bo1, nullptr, t1, 3840, 1024, 1024, 1024);
  for (int c = 0; c < 4; ++c) {
    k_transpose<<<tg, tb, 0, stream>>>(ho2 + c * 1024, wT, 1024, 1024, 4096);
    k_gemm<4><<<dim3(30, 8), 256, 0, stream>>>(t1, wT, bo2 + c * 1024, nullptr,
                                               (float*)d_out + c * 1024, 3840, 1024, 1024, 4096);
  }
  // ends head
  k_transpose<<<tg, tb, 0, stream>>>(he1, wT, 1024, 1024, 1024);
  k_gemm<1><<<dim3(2, 8), 256, 0, stream>>>(xe, wT, be1, nullptr, t2, 240, 1024, 1024, 1024);
  k_ends<<<240, 256, 0, stream>>>(t2, he2, be2, (float*)d_out + (size_t)3840 * 4096);
}

// Round 7
// 1525.832 us; speedup vs baseline: 4.0126x; 1.7853x over previous
//
#include <hip/hip_runtime.h>
#include <hip/hip_bf16.h>
#include <math.h>

namespace {

constexpr int kS = 1020, kD = 1024, kTPB = 17, kDH = 64;
constexpr int kVOBS = 4096, kVACT = 16;
constexpr int kBS = 4080;          // B*S
constexpr float kEPS = 1e-3f;

typedef float f32x4 __attribute__((ext_vector_type(4)));
typedef __bf16 bfx8 __attribute__((ext_vector_type(8)));
typedef unsigned short u16;
typedef u16 us8 __attribute__((ext_vector_type(8)));
typedef u16 us4 __attribute__((ext_vector_type(4)));

__device__ __forceinline__ float bf2f(u16 u) {
  union { unsigned int i; float f; } v; v.i = (unsigned int)u << 16; return v.f;
}
__device__ __forceinline__ u16 f2bf(float f) {
  union { float f; unsigned int i; } v; v.f = f;
  unsigned int r = v.i + 0x7FFFu + ((v.i >> 16) & 1u);
  return (u16)(r >> 16);
}

// ---------- embed
__global__ void k_embed(const int* __restrict__ tokens, const float* __restrict__ pos_emb,
                        const float* __restrict__ emb_obs, const float* __restrict__ emb_act,
                        float* __restrict__ x) {
  int bs = blockIdx.x;
  int s = bs % kS;
  int tk = tokens[bs];
  bool obs = (s % kTPB) < (kTPB - 1);
  const float* e;
  if (obs) { int t2 = tk < kVOBS - 1 ? tk : kVOBS - 1; e = emb_obs + (size_t)t2 * kD; }
  else     { int t2 = tk < kVACT - 1 ? tk : kVACT - 1; e = emb_act + (size_t)t2 * kD; }
  int c = threadIdx.x * 4;
  float4 ev = *(const float4*)(e + c);
  float4 pv = *(const float4*)(pos_emb + (size_t)s * kD + c);
  float4 o; o.x = ev.x + pv.x; o.y = ev.y + pv.y; o.z = ev.z + pv.z; o.w = ev.w + pv.w;
  *(float4*)(x + (size_t)bs * kD + c) = o;
}

// ---------- bias pack: bqkv[l][0:1024)=bq[l], [1024:2048)=bk[l], [2048:3072)=bv[l]
__global__ void k_pack_bias(const float* __restrict__ bq, const float* __restrict__ bk,
                            const float* __restrict__ bv, float* __restrict__ bqkv) {
  int idx = blockIdx.x * 256 + threadIdx.x;      // 0..12287
  int l = idx / 3072, rem = idx % 3072;
  int sel = rem >> 10, cc = rem & 1023;
  const float* src = sel == 0 ? bq : (sel == 1 ? bk : bv);
  bqkv[idx] = src[l * kD + cc];
}

// ---------- LayerNorm: f32 in -> bf16 out.
__global__ void k_ln(const float* __restrict__ x, const float* __restrict__ g,
                     const float* __restrict__ b, u16* __restrict__ out) {
  int row = blockIdx.x;
  int t = threadIdx.x;
  const float* xr = x + (size_t)row * kD;
  float4 v = *(const float4*)(xr + t * 4);
  float s1 = v.x + v.y + v.z + v.w;
  float s2 = v.x * v.x + v.y * v.y + v.z * v.z + v.w * v.w;
  #pragma unroll
  for (int m = 32; m; m >>= 1) { s1 += __shfl_xor(s1, m); s2 += __shfl_xor(s2, m); }
  __shared__ float ls1[4], ls2[4];
  int w = t >> 6;
  if ((t & 63) == 0) { ls1[w] = s1; ls2[w] = s2; }
  __syncthreads();
  float S1 = ls1[0] + ls1[1] + ls1[2] + ls1[3];
  float S2 = ls2[0] + ls2[1] + ls2[2] + ls2[3];
  float mean = S1 * (1.0f / kD);
  float var = S2 * (1.0f / kD) - mean * mean;
  float rs = rsqrtf(var + kEPS);
  int c = t * 4;
  float4 gv = *(const float4*)(g + c);
  float4 bv = *(const float4*)(b + c);
  us4 o;
  o[0] = f2bf((v.x - mean) * rs * gv.x + bv.x);
  o[1] = f2bf((v.y - mean) * rs * gv.y + bv.y);
  o[2] = f2bf((v.z - mean) * rs * gv.z + bv.z);
  o[3] = f2bf((v.w - mean) * rs * gv.w + bv.w);
  *(us4*)(out + (size_t)row * kD + c) = o;
}

// ---------- transpose + f32->bf16: out[c][r] = in[r*ld + c]
__global__ void k_transpose(const float* __restrict__ in, u16* __restrict__ out,
                            int R, int C, int ld) {
  __shared__ float tile[32][33];
  int tx = threadIdx.x, ty = threadIdx.y;
  int c0 = blockIdx.x * 32, r0 = blockIdx.y * 32;
  #pragma unroll
  for (int i = 0; i < 4; ++i)
    tile[ty + i * 8][tx] = in[(size_t)(r0 + ty + i * 8) * ld + c0 + tx];
  __syncthreads();
  #pragma unroll
  for (int i = 0; i < 4; ++i)
    out[(size_t)(c0 + ty + i * 8) * R + r0 + tx] = f2bf(tile[tx][ty + i * 8]);
}

// ---------- MFMA GEMM: out[M][ldo] = A[M][K](bf16) * Bt[N][K](bf16)^T + bias(f32)
// BM x 128 tile, BK=32, 4 waves (2x2), wave covers (BM/2) x 64.
// EPI: 0 bf16, 1 bf16 relu, 2 bf16 gelu, 3 f32 resid+val, 4 f32 store
template <int EPI, int BM>
__global__ void __launch_bounds__(256)
k_gemm(const u16* __restrict__ A, const u16* __restrict__ Bt, const float* __restrict__ bias,
       const float* __restrict__ resid, void* __restrict__ out, int M, int N, int K, int ldo) {
  constexpr int MFRAG = BM / 32;            // frags per wave in M (4 or 2)
  __shared__ alignas(16) u16 As[BM][40];    // +8 pad: 80B stride, free 2-way
  __shared__ alignas(16) u16 Bs[128][40];
  int tid = threadIdx.x;
  int m0 = blockIdx.x * BM, n0 = blockIdx.y * 128;
  int lane = tid & 63, wv = tid >> 6;
  int wm = wv >> 1, wn = wv & 1;
  f32x4 acc[MFRAG][4] = {};
  us8 zero8;
  #pragma unroll
  for (int z = 0; z < 8; ++z) zero8[z] = 0;
  int ko = (lane >> 4) * 8;

  for (int k0 = 0; k0 < K; k0 += 32) {
    #pragma unroll
    for (int it = 0; it < BM / 64; ++it) {   // A tile: BM*4 us8 chunks
      int idx = it * 256 + tid;
      int r = idx >> 2;
      int c8 = (idx & 3) * 8;
      int gr = m0 + r;
      us8 va = (gr < M) ? *(const us8*)(A + (size_t)gr * K + k0 + c8) : zero8;
      *(us8*)(&As[r][c8]) = va;
    }
    #pragma unroll
    for (int it = 0; it < 2; ++it) {         // B tile: 512 us8 chunks
      int idx = it * 256 + tid;
      int r = idx >> 2;
      int c8 = (idx & 3) * 8;
      us8 vb = *(const us8*)(Bt + (size_t)(n0 + r) * K + k0 + c8);
      *(us8*)(&Bs[r][c8]) = vb;
    }
    __syncthreads();
    bfx8 af[MFRAG], bfr[4];
    #pragma unroll
    for (int mf = 0; mf < MFRAG; ++mf)
      af[mf] = *(const bfx8*)(&As[wm * (BM / 2) + mf * 16 + (lane & 15)][ko]);
    #pragma unroll
    for (int nf = 0; nf < 4; ++nf)
      bfr[nf] = *(const bfx8*)(&Bs[wn * 64 + nf * 16 + (lane & 15)][ko]);
    #pragma unroll
    for (int mf = 0; mf < MFRAG; ++mf)
      #pragma unroll
      for (int nf = 0; nf < 4; ++nf)
        acc[mf][nf] = __builtin_amdgcn_mfma_f32_16x16x32_bf16(af[mf], bfr[nf], acc[mf][nf], 0, 0, 0);
    __syncthreads();
  }

  #pragma unroll
  for (int mf = 0; mf < MFRAG; ++mf) {
    #pragma unroll
    for (int nf = 0; nf < 4; ++nf) {
      int gcol = n0 + wn * 64 + nf * 16 + (lane & 15);
      float bv = bias ? bias[gcol] : 0.0f;
      #pragma unroll
      for (int r = 0; r < 4; ++r) {
        int grow = m0 + wm * (BM / 2) + mf * 16 + (lane >> 4) * 4 + r;
        if (grow >= M) continue;
        float val = acc[mf][nf][r] + bv;
        size_t off2 = (size_t)grow * ldo + gcol;
        if (EPI == 0) {
          ((u16*)out)[off2] = f2bf(val);
        } else if (EPI == 1) {
          ((u16*)out)[off2] = f2bf(val > 0.f ? val : 0.f);
        } else if (EPI == 2) {
          ((u16*)out)[off2] = f2bf(0.5f * val * (1.f + erff(val * 0.70710678118654752440f)));
        } else if (EPI == 3) {
          ((float*)out)[off2] = resid[off2] + val;
        } else {
          ((float*)out)[off2] = val;
        }
      }
    }
  }
}

// ---------- MFMA flash attention (swapped-operand). q/k/v row stride = ldin.
__device__ __forceinline__ int swz(int row, int colu16) {
  return (row * 64 + colu16) ^ ((row & 7) << 3) ^ ((row & 24) << 1);
}

__global__ void __launch_bounds__(256)
k_attn(const u16* __restrict__ q, const u16* __restrict__ k, const u16* __restrict__ v,
       u16* __restrict__ o, int ldin) {
  __shared__ u16 Kl[64 * 64];
  __shared__ u16 Vt[64 * 64];
  const int qb = blockIdx.x * 64;
  const int bh = blockIdx.y;
  const int b = bh >> 4, hh = bh & 15;
  const int tid = threadIdx.x;
  const int lane = tid & 63, w = tid >> 6;
  const int g = lane >> 4, c = lane & 15;
  const int q0 = qb + w * 16;
  const size_t base = (size_t)(b * kS) * ldin + hh * kDH;

  bfx8 qf0, qf1;
  {
    int qr = q0 + c; if (qr >= kS) qr = kS - 1;
    const u16* qp = q + base + (size_t)qr * ldin + g * 8;
    qf0 = *(const bfx8*)(qp);
    qf1 = *(const bfx8*)(qp + 32);
  }

  float mst = -1e30f, lsum = 0.f;
  f32x4 ot[4] = {};

  const int ntiles = blockIdx.x + 1;
  for (int t = 0; t < ntiles; ++t) {
    const int kt = t * 64;
    {
      int kr = tid >> 2, ds2 = (tid & 3) * 16;
      int kg = kt + kr; if (kg >= kS) kg = kS - 1;
      const u16* kp = k + base + (size_t)kg * ldin + ds2;
      us8 a0 = *(const us8*)(kp);
      us8 a1 = *(const us8*)(kp + 8);
      *(us8*)(&Kl[swz(kr, ds2)]) = a0;
      *(us8*)(&Kl[swz(kr, ds2 + 8)]) = a1;
      const u16* vp = v + base + (size_t)kg * ldin + ds2;
      us8 b0 = *(const us8*)(vp);
      us8 b1 = *(const us8*)(vp + 8);
      #pragma unroll
      for (int i2 = 0; i2 < 8; ++i2) Vt[swz(ds2 + i2, kr)] = b0[i2];
      #pragma unroll
      for (int i2 = 0; i2 < 8; ++i2) Vt[swz(ds2 + 8 + i2, kr)] = b1[i2];
    }
    __syncthreads();

    f32x4 s[4];
    #pragma unroll
    for (int kb = 0; kb < 4; ++kb) {
      bfx8 kf0 = *(const bfx8*)(&Kl[swz(kb * 16 + c, g * 8)]);
      bfx8 kf1 = *(const bfx8*)(&Kl[swz(kb * 16 + c, g * 8 + 32)]);
      f32x4 acc = {};
      acc = __builtin_amdgcn_mfma_f32_16x16x32_bf16(kf0, qf0, acc, 0, 0, 0);
      acc = __builtin_amdgcn_mfma_f32_16x16x32_bf16(kf1, qf1, acc, 0, 0, 0);
      s[kb] = acc;
    }

    const int qg = q0 + c;
    const bool diag = (kt + 63 > q0);
    float p[4][4];
    float tmax = -1e30f;
    #pragma unroll
    for (int kb = 0; kb < 4; ++kb)
      #pragma unroll
      for (int r = 0; r < 4; ++r) {
        float val = s[kb][r] * 0.125f;
        if (diag && (kt + kb * 16 + g * 4 + r > qg)) val = -1e30f;
        p[kb][r] = val;
        tmax = fmaxf(tmax, val);
      }
    tmax = fmaxf(tmax, __shfl_xor(tmax, 16));
    tmax = fmaxf(tmax, __shfl_xor(tmax, 32));
    float mnew = fmaxf(mst, tmax);
    float alpha = __expf(mst - mnew);
    float psum = 0.f;
    #pragma unroll
    for (int kb = 0; kb < 4; ++kb)
      #pragma unroll
      for (int r = 0; r < 4; ++r) {
        float e = __expf(p[kb][r] - mnew);
        p[kb][r] = e;
        psum += e;
      }
    psum += __shfl_xor(psum, 16);
    psum += __shfl_xor(psum, 32);
    lsum = lsum * alpha + psum;
    mst = mnew;
    #pragma unroll
    for (int db = 0; db < 4; ++db) {
      ot[db][0] *= alpha; ot[db][1] *= alpha;
      ot[db][2] *= alpha; ot[db][3] *= alpha;
    }

    #pragma unroll
    for (int h = 0; h < 2; ++h) {
      bfx8 pf;
      #pragma unroll
      for (int j = 0; j < 8; ++j)
        pf[j] = (__bf16)p[2 * h + (j >> 2)][j & 3];
      #pragma unroll
      for (int db = 0; db < 4; ++db) {
        us4 lo = *(const us4*)(&Vt[swz(16 * db + c, 32 * h + 4 * g)]);
        us4 hi = *(const us4*)(&Vt[swz(16 * db + c, 32 * h + 16 + 4 * g)]);
        union { us8 u; bfx8 bf; } cv;
        cv.u[0] = lo[0]; cv.u[1] = lo[1]; cv.u[2] = lo[2]; cv.u[3] = lo[3];
        cv.u[4] = hi[0]; cv.u[5] = hi[1]; cv.u[6] = hi[2]; cv.u[7] = hi[3];
        ot[db] = __builtin_amdgcn_mfma_f32_16x16x32_bf16(cv.bf, pf, ot[db], 0, 0, 0);
      }
    }
    __syncthreads();
  }

  if (q0 + c < kS) {
    float inv = 1.0f / lsum;
    u16* op = o + (size_t)(b * kS) * kD + hh * kDH + (size_t)(q0 + c) * kD;
    #pragma unroll
    for (int db = 0; db < 4; ++db)
      #pragma unroll
      for (int r = 0; r < 4; ++r)
        op[16 * db + 4 * g + r] = f2bf(ot[db][r] * inv);
  }
}

// ---------- gathers
__global__ void k_gather_obs(const u16* __restrict__ xf, u16* __restrict__ xo) {
  int r = blockIdx.x;
  int b = r / 960, rr = r % 960;
  int j = rr & 15, blk = rr >> 4;
  int s = blk * kTPB + j + (j == 15 ? 1 : 0);
  const unsigned int* src = (const unsigned int*)(xf + ((size_t)(b * kS + s)) * kD);
  unsigned int* dst = (unsigned int*)(xo + (size_t)r * kD);
  dst[threadIdx.x] = src[threadIdx.x];
  dst[threadIdx.x + 256] = src[threadIdx.x + 256];
}
__global__ void k_gather_act(const u16* __restrict__ xf, u16* __restrict__ xe) {
  int r = blockIdx.x;
  int b = r / 60, rr = r % 60;
  int s = rr * kTPB + (kTPB - 1);
  const unsigned int* src = (const unsigned int*)(xf + ((size_t)(b * kS + s)) * kD);
  unsigned int* dst = (unsigned int*)(xe + (size_t)r * kD);
  dst[threadIdx.x] = src[threadIdx.x];
  dst[threadIdx.x + 256] = src[threadIdx.x + 256];
}

// ---------- ends head (f32 out)
__global__ void k_ends(const u16* __restrict__ t2, const float* __restrict__ he2,
                       const float* __restrict__ be2, float* __restrict__ out) {
  int r = blockIdx.x;
  int t = threadIdx.x;
  float p0 = 0.f, p1 = 0.f;
  for (int j = t; j < kD; j += 256) {
    float xv = bf2f(t2[(size_t)r * kD + j]);
    p0 += xv * he2[j * 2];
    p1 += xv * he2[j * 2 + 1];
  }
  #pragma unroll
  for (int msk = 32; msk; msk >>= 1) { p0 += __shfl_xor(p0, msk); p1 += __shfl_xor(p1, msk); }
  __shared__ float l0[4], l1[4];
  int w = t >> 6;
  if ((t & 63) == 0) { l0[w] = p0; l1[w] = p1; }
  __syncthreads();
  if (t == 0) {
    out[r * 2 + 0] = l0[0] + l0[1] + l0[2] + l0[3] + be2[0];
    out[r * 2 + 1] = l1[0] + l1[1] + l1[2] + l1[3] + be2[1];
  }
}

} // namespace

extern "C" void kernel_launch(void* const* d_in, const int* in_sizes, int n_in,
                              void* d_out, int out_size, void* d_ws, size_t ws_size,
                              hipStream_t stream) {
  const int*   tokens  = (const int*)  d_in[0];
  const float* pos_emb = (const float*)d_in[1];
  const float* emb_obs = (const float*)d_in[2];
  const float* emb_act = (const float*)d_in[3];
  const float* ln1_g = (const float*)d_in[4];
  const float* ln1_b = (const float*)d_in[5];
  const float* wq = (const float*)d_in[6];
  const float* bq = (const float*)d_in[7];
  const float* wk = (const float*)d_in[8];
  const float* bk = (const float*)d_in[9];
  const float* wv = (const float*)d_in[10];
  const float* bv = (const float*)d_in[11];
  const float* wo = (const float*)d_in[12];
  const float* bo = (const float*)d_in[13];
  const float* ln2_g = (const float*)d_in[14];
  const float* ln2_b = (const float*)d_in[15];
  const float* w1 = (const float*)d_in[16];
  const float* b1 = (const float*)d_in[17];
  const float* w2 = (const float*)d_in[18];
  const float* b2 = (const float*)d_in[19];
  const float* lnf_g = (const float*)d_in[20];
  const float* lnf_b = (const float*)d_in[21];
  const float* ho1 = (const float*)d_in[22];
  const float* bo1 = (const float*)d_in[23];
  const float* ho2 = (const float*)d_in[24];
  const float* bo2 = (const float*)d_in[25];
  const float* he1 = (const float*)d_in[26];
  const float* be1 = (const float*)d_in[27];
  const float* he2 = (const float*)d_in[28];
  const float* be2 = (const float*)d_in[29];
  (void)in_sizes; (void)n_in; (void)out_size; (void)ws_size;

  // ---- workspace: ~66.6 MB
  char* ws = (char*)d_ws;
  size_t off = 0;
  auto alloc = [&](size_t bytes) -> char* {
    char* p = ws + off; off += (bytes + 255) & ~(size_t)255; return p;
  };
  u16*   wTbig = (u16*)alloc((size_t)4096 * 1024 * 2);    // 8 MB stacked B^T
  float* x  = (float*)alloc((size_t)kBS * kD * 4);        // 16.71 MB residual
  u16*   h  = (u16*)alloc((size_t)kBS * kD * 2);          // 8.36 MB LN out
  char*  scr = alloc((size_t)kBS * 4096 * 2);             // 33.42 MB
  float* bqkv = (float*)alloc((size_t)4 * 3072 * 4);      // 48 KB packed QKV bias
  const size_t slotB = (size_t)kBS * kD * 2;
  // layer-phase aliases
  u16* qkv = (u16*)scr;                     // [4080][3072] (25.07 MB)
  u16* ob  = (u16*)(scr + (size_t)kBS * 3072 * 2);  // [4080][1024] (8.36 MB)
  u16* mid = (u16*)scr;                     // [4080][4096] (33.42 MB), qkv+ob dead
  // post-loop aliases
  u16* xf = (u16*)scr;
  u16* xo = (u16*)(scr + slotB);
  u16* t1 = (u16*)(scr + 2 * slotB);
  u16* xe = (u16*)(scr + 3 * slotB);
  u16* t2 = (u16*)(scr + 3 * slotB + (size_t)240 * kD * 2 + 256);

  dim3 tb(32, 8);
  dim3 tg(32, 32);
  k_embed<<<kBS, 256, 0, stream>>>(tokens, pos_emb, emb_obs, emb_act, x);
  k_pack_bias<<<48, 256, 0, stream>>>(bq, bk, bv, bqkv);

  for (int i = 0; i < 4; ++i) {
    const size_t wOff = (size_t)i * kD * kD;
    k_ln<<<kBS, 256, 0, stream>>>(x, ln1_g + i * kD, ln1_b + i * kD, h);

    // fused QKV: wTbig rows [0,1024)=wq^T, [1024,2048)=wk^T, [2048,3072)=wv^T
    k_transpose<<<tg, tb, 0, stream>>>(wq + wOff, wTbig, 1024, 1024, 1024);
    k_transpose<<<tg, tb, 0, stream>>>(wk + wOff, wTbig + (size_t)1024 * 1024, 1024, 1024, 1024);
    k_transpose<<<tg, tb, 0, stream>>>(wv + wOff, wTbig + (size_t)2048 * 1024, 1024, 1024, 1024);
    k_gemm<0, 128><<<dim3(32, 24), 256, 0, stream>>>(h, wTbig, bqkv + i * 3072, nullptr, qkv,
                                                     kBS, 3072, 1024, 3072);

    k_attn<<<dim3(16, 64), 256, 0, stream>>>(qkv, qkv + 1024, qkv + 2048, ob, 3072);

    k_transpose<<<tg, tb, 0, stream>>>(wo + wOff, wTbig, 1024, 1024, 1024);
    k_gemm<3, 64><<<dim3(64, 8), 256, 0, stream>>>(ob, wTbig, bo + i * kD, x, x,
                                                   kBS, 1024, 1024, 1024);

    k_ln<<<kBS, 256, 0, stream>>>(x, ln2_g + i * kD, ln2_b + i * kD, h);

    // FFN1: mid = gelu(h @ w1 + b1), N=4096 in one GEMM
    for (int c = 0; c < 4; ++c)
      k_transpose<<<tg, tb, 0, stream>>>(w1 + (size_t)i * kD * 4096 + c * 1024,
                                         wTbig + (size_t)c * 1024 * 1024, 1024, 1024, 4096);
    k_gemm<2, 128><<<dim3(32, 32), 256, 0, stream>>>(h, wTbig, b1 + (size_t)i * 4096, nullptr,
                                                     mid, kBS, 4096, 1024, 4096);
    // FFN2: x += mid @ w2 + b2, K=4096 in one GEMM
    k_transpose<<<dim3(32, 128), tb, 0, stream>>>(w2 + (size_t)i * 4096 * kD, wTbig,
                                                  4096, 1024, 1024);
    k_gemm<3, 64><<<dim3(64, 8), 256, 0, stream>>>(mid, wTbig, b2 + i * kD, x, x,
                                                   kBS, 1024, 4096, 1024);
  }

  k_ln<<<kBS, 256, 0, stream>>>(x, lnf_g, lnf_b, xf);
  k_gather_obs<<<3840, 256, 0, stream>>>(xf, xo);
  k_gather_act<<<240, 256, 0, stream>>>(xf, xe);

  // obs head
  k_transpose<<<tg, tb, 0, stream>>>(ho1, wTbig, 1024, 1024, 1024);
  k_gemm<1, 64><<<dim3(60, 8), 256, 0, stream>>>(xo, wTbig, bo1, nullptr, t1,
                                                 3840, 1024, 1024, 1024);
  for (int c = 0; c < 4; ++c)
    k_transpose<<<tg, tb, 0, stream>>>(ho2 + c * 1024, wTbig + (size_t)c * 1024 * 1024,
                                       1024, 1024, 4096);
  k_gemm<4, 128><<<dim3(30, 32), 256, 0, stream>>>(t1, wTbig, bo2, nullptr,
                                                   (float*)d_out, 3840, 4096, 1024, 4096);
  // ends head
  k_transpose<<<tg, tb, 0, stream>>>(he1, wTbig, 1024, 1024, 1024);
  k_gemm<1, 64><<<dim3(4, 8), 256, 0, stream>>>(xe, wTbig, be1, nullptr, t2,
                                                240, 1024, 1024, 1024);
  k_ends<<<240, 256, 0, stream>>>(t2, he2, be2, (float*)d_out + (size_t)3840 * 4096);
}

// Round 8
// 1458.341 us; speedup vs baseline: 4.1984x; 1.0463x over previous
//
#include <hip/hip_runtime.h>
#include <hip/hip_bf16.h>
#include <math.h>

namespace {

constexpr int kS = 1020, kD = 1024, kTPB = 17, kDH = 64;
constexpr int kVOBS = 4096, kVACT = 16;
constexpr int kBS = 4080;          // B*S
constexpr float kEPS = 1e-3f;

typedef float f32x4 __attribute__((ext_vector_type(4)));
typedef __bf16 bfx8 __attribute__((ext_vector_type(8)));
typedef unsigned short u16;
typedef u16 us8 __attribute__((ext_vector_type(8)));
typedef u16 us4 __attribute__((ext_vector_type(4)));

__device__ __forceinline__ float bf2f(u16 u) {
  union { unsigned int i; float f; } v; v.i = (unsigned int)u << 16; return v.f;
}
__device__ __forceinline__ u16 f2bf(float f) {
  union { float f; unsigned int i; } v; v.f = f;
  unsigned int r = v.i + 0x7FFFu + ((v.i >> 16) & 1u);
  return (u16)(r >> 16);
}

// ---------- embed
__global__ void k_embed(const int* __restrict__ tokens, const float* __restrict__ pos_emb,
                        const float* __restrict__ emb_obs, const float* __restrict__ emb_act,
                        float* __restrict__ x) {
  int bs = blockIdx.x;
  int s = bs % kS;
  int tk = tokens[bs];
  bool obs = (s % kTPB) < (kTPB - 1);
  const float* e;
  if (obs) { int t2 = tk < kVOBS - 1 ? tk : kVOBS - 1; e = emb_obs + (size_t)t2 * kD; }
  else     { int t2 = tk < kVACT - 1 ? tk : kVACT - 1; e = emb_act + (size_t)t2 * kD; }
  int c = threadIdx.x * 4;
  float4 ev = *(const float4*)(e + c);
  float4 pv = *(const float4*)(pos_emb + (size_t)s * kD + c);
  float4 o; o.x = ev.x + pv.x; o.y = ev.y + pv.y; o.z = ev.z + pv.z; o.w = ev.w + pv.w;
  *(float4*)(x + (size_t)bs * kD + c) = o;
}

// ---------- bias pack (QKV)
__global__ void k_pack_bias(const float* __restrict__ bq, const float* __restrict__ bk,
                            const float* __restrict__ bv, float* __restrict__ bqkv) {
  int idx = blockIdx.x * 256 + threadIdx.x;      // 0..12287
  int l = idx / 3072, rem = idx % 3072;
  int sel = rem >> 10, cc = rem & 1023;
  const float* src = sel == 0 ? bq : (sel == 1 ? bk : bv);
  bqkv[idx] = src[l * kD + cc];
}

// ---------- LayerNorm: f32 in -> bf16 out.
__global__ void k_ln(const float* __restrict__ x, const float* __restrict__ g,
                     const float* __restrict__ b, u16* __restrict__ out) {
  int row = blockIdx.x;
  int t = threadIdx.x;
  const float* xr = x + (size_t)row * kD;
  float4 v = *(const float4*)(xr + t * 4);
  float s1 = v.x + v.y + v.z + v.w;
  float s2 = v.x * v.x + v.y * v.y + v.z * v.z + v.w * v.w;
  #pragma unroll
  for (int m = 32; m; m >>= 1) { s1 += __shfl_xor(s1, m); s2 += __shfl_xor(s2, m); }
  __shared__ float ls1[4], ls2[4];
  int w = t >> 6;
  if ((t & 63) == 0) { ls1[w] = s1; ls2[w] = s2; }
  __syncthreads();
  float S1 = ls1[0] + ls1[1] + ls1[2] + ls1[3];
  float S2 = ls2[0] + ls2[1] + ls2[2] + ls2[3];
  float mean = S1 * (1.0f / kD);
  float var = S2 * (1.0f / kD) - mean * mean;
  float rs = rsqrtf(var + kEPS);
  int c = t * 4;
  float4 gv = *(const float4*)(g + c);
  float4 bv = *(const float4*)(b + c);
  us4 o;
  o[0] = f2bf((v.x - mean) * rs * gv.x + bv.x);
  o[1] = f2bf((v.y - mean) * rs * gv.y + bv.y);
  o[2] = f2bf((v.z - mean) * rs * gv.z + bv.z);
  o[3] = f2bf((v.w - mean) * rs * gv.w + bv.w);
  *(us4*)(out + (size_t)row * kD + c) = o;
}

// ---------- transpose + f32->bf16
__global__ void k_transpose(const float* __restrict__ in, u16* __restrict__ out,
                            int R, int C, int ld) {
  __shared__ float tile[32][33];
  int tx = threadIdx.x, ty = threadIdx.y;
  int c0 = blockIdx.x * 32, r0 = blockIdx.y * 32;
  #pragma unroll
  for (int i = 0; i < 4; ++i)
    tile[ty + i * 8][tx] = in[(size_t)(r0 + ty + i * 8) * ld + c0 + tx];
  __syncthreads();
  #pragma unroll
  for (int i = 0; i < 4; ++i)
    out[(size_t)(c0 + ty + i * 8) * R + r0 + tx] = f2bf(tile[tx][ty + i * 8]);
}

// ---------- MFMA GEMM with global_load_lds staging (m97 pattern) + XCD swizzle.
// out[M][ldo] = A[M][K](bf16) * Bt[N][K](bf16)^T + bias(f32).
// BM x 128 tile, BK=32; LDS linear 64B rows, 16B-chunk XOR swizzle
// (slot = chunk ^ ((row>>1)&3)) applied on BOTH global-source and LDS-read sides.
// EPI: 0 bf16, 1 bf16 relu, 2 bf16 gelu, 3 f32 resid+val, 4 f32 store
template <int EPI, int BM>
__global__ void __launch_bounds__(256)
k_gemm(const u16* __restrict__ A, const u16* __restrict__ Bt, const float* __restrict__ bias,
       const float* __restrict__ resid, void* __restrict__ out, int M, int N, int K, int ldo) {
  constexpr int MFRAG = BM / 32;
  __shared__ alignas(16) u16 As[BM * 32];    // [row][32 u16], linear
  __shared__ alignas(16) u16 Bs[128 * 32];
  int tid = threadIdx.x;
  // XCD-aware bijective block swizzle (all call-site grids are multiples of 8)
  int nwg = gridDim.x * gridDim.y;
  int lin = blockIdx.y * gridDim.x + blockIdx.x;
  int swzid = (lin & 7) * (nwg >> 3) + (lin >> 3);
  int m0 = (swzid % gridDim.x) * BM;
  int n0 = (swzid / gridDim.x) * 128;
  int lane = tid & 63, wv = tid >> 6;
  int wm = wv >> 1, wn = wv & 1;
  f32x4 acc[MFRAG][4] = {};

  for (int k0 = 0; k0 < K; k0 += 32) {
    #pragma unroll
    for (int n = 0; n < BM / 64; ++n) {      // A: BM rows x 4 chunks(16B)
      int u = n * 256 + wv * 64 + lane;
      int r = u >> 2, ch = u & 3;
      int gr = m0 + r; if (gr >= M) gr = M - 1;   // clamp: dup rows never stored
      int cg = ch ^ ((r >> 1) & 3);
      const u16* src = A + (size_t)gr * K + k0 + cg * 8;
      __builtin_amdgcn_global_load_lds(
          (const __attribute__((address_space(1))) unsigned int*)src,
          (__attribute__((address_space(3))) unsigned int*)&As[(size_t)(n * 256 + wv * 64) * 8],
          16, 0, 0);
    }
    #pragma unroll
    for (int n = 0; n < 2; ++n) {            // B: 128 rows x 4 chunks
      int u = n * 256 + wv * 64 + lane;
      int r = u >> 2, ch = u & 3;
      int cg = ch ^ ((r >> 1) & 3);
      const u16* src = Bt + (size_t)(n0 + r) * K + k0 + cg * 8;
      __builtin_amdgcn_global_load_lds(
          (const __attribute__((address_space(1))) unsigned int*)src,
          (__attribute__((address_space(3))) unsigned int*)&Bs[(size_t)(n * 256 + wv * 64) * 8],
          16, 0, 0);
    }
    __syncthreads();   // compiler emits vmcnt(0) drain here (m97 structure)

    bfx8 af[MFRAG], bfr[4];
    int ch = lane >> 4;                      // logical k-chunk for this lane
    #pragma unroll
    for (int mf = 0; mf < MFRAG; ++mf) {
      int row = wm * (BM / 2) + mf * 16 + (lane & 15);
      af[mf] = *(const bfx8*)(&As[row * 32 + ((ch ^ ((row >> 1) & 3)) << 3)]);
    }
    #pragma unroll
    for (int nf = 0; nf < 4; ++nf) {
      int row = wn * 64 + nf * 16 + (lane & 15);
      bfr[nf] = *(const bfx8*)(&Bs[row * 32 + ((ch ^ ((row >> 1) & 3)) << 3)]);
    }
    #pragma unroll
    for (int mf = 0; mf < MFRAG; ++mf)
      #pragma unroll
      for (int nf = 0; nf < 4; ++nf)
        acc[mf][nf] = __builtin_amdgcn_mfma_f32_16x16x32_bf16(af[mf], bfr[nf], acc[mf][nf], 0, 0, 0);
    __syncthreads();
  }

  #pragma unroll
  for (int mf = 0; mf < MFRAG; ++mf) {
    #pragma unroll
    for (int nf = 0; nf < 4; ++nf) {
      int gcol = n0 + wn * 64 + nf * 16 + (lane & 15);
      float bv = bias ? bias[gcol] : 0.0f;
      #pragma unroll
      for (int r = 0; r < 4; ++r) {
        int grow = m0 + wm * (BM / 2) + mf * 16 + (lane >> 4) * 4 + r;
        if (grow >= M) continue;
        float val = acc[mf][nf][r] + bv;
        size_t off2 = (size_t)grow * ldo + gcol;
        if (EPI == 0) {
          ((u16*)out)[off2] = f2bf(val);
        } else if (EPI == 1) {
          ((u16*)out)[off2] = f2bf(val > 0.f ? val : 0.f);
        } else if (EPI == 2) {
          ((u16*)out)[off2] = f2bf(0.5f * val * (1.f + erff(val * 0.70710678118654752440f)));
        } else if (EPI == 3) {
          ((float*)out)[off2] = resid[off2] + val;
        } else {
          ((float*)out)[off2] = val;
        }
      }
    }
  }
}

// ---------- MFMA flash attention (swapped-operand). q/k/v row stride = ldin.
__device__ __forceinline__ int swz(int row, int colu16) {
  return (row * 64 + colu16) ^ ((row & 7) << 3) ^ ((row & 24) << 1);
}

__global__ void __launch_bounds__(256)
k_attn(const u16* __restrict__ q, const u16* __restrict__ k, const u16* __restrict__ v,
       u16* __restrict__ o, int ldin) {
  __shared__ u16 Kl[64 * 64];
  __shared__ u16 Vt[64 * 64];
  const int qb = blockIdx.x * 64;
  const int bh = blockIdx.y;
  const int b = bh >> 4, hh = bh & 15;
  const int tid = threadIdx.x;
  const int lane = tid & 63, w = tid >> 6;
  const int g = lane >> 4, c = lane & 15;
  const int q0 = qb + w * 16;
  const size_t base = (size_t)(b * kS) * ldin + hh * kDH;

  bfx8 qf0, qf1;
  {
    int qr = q0 + c; if (qr >= kS) qr = kS - 1;
    const u16* qp = q + base + (size_t)qr * ldin + g * 8;
    qf0 = *(const bfx8*)(qp);
    qf1 = *(const bfx8*)(qp + 32);
  }

  float mst = -1e30f, lsum = 0.f;
  f32x4 ot[4] = {};

  const int ntiles = blockIdx.x + 1;
  for (int t = 0; t < ntiles; ++t) {
    const int kt = t * 64;
    {
      int kr = tid >> 2, ds2 = (tid & 3) * 16;
      int kg = kt + kr; if (kg >= kS) kg = kS - 1;
      const u16* kp = k + base + (size_t)kg * ldin + ds2;
      us8 a0 = *(const us8*)(kp);
      us8 a1 = *(const us8*)(kp + 8);
      *(us8*)(&Kl[swz(kr, ds2)]) = a0;
      *(us8*)(&Kl[swz(kr, ds2 + 8)]) = a1;
      const u16* vp = v + base + (size_t)kg * ldin + ds2;
      us8 b0 = *(const us8*)(vp);
      us8 b1 = *(const us8*)(vp + 8);
      #pragma unroll
      for (int i2 = 0; i2 < 8; ++i2) Vt[swz(ds2 + i2, kr)] = b0[i2];
      #pragma unroll
      for (int i2 = 0; i2 < 8; ++i2) Vt[swz(ds2 + 8 + i2, kr)] = b1[i2];
    }
    __syncthreads();

    f32x4 s[4];
    #pragma unroll
    for (int kb = 0; kb < 4; ++kb) {
      bfx8 kf0 = *(const bfx8*)(&Kl[swz(kb * 16 + c, g * 8)]);
      bfx8 kf1 = *(const bfx8*)(&Kl[swz(kb * 16 + c, g * 8 + 32)]);
      f32x4 acc = {};
      acc = __builtin_amdgcn_mfma_f32_16x16x32_bf16(kf0, qf0, acc, 0, 0, 0);
      acc = __builtin_amdgcn_mfma_f32_16x16x32_bf16(kf1, qf1, acc, 0, 0, 0);
      s[kb] = acc;
    }

    const int qg = q0 + c;
    const bool diag = (kt + 63 > q0);
    float p[4][4];
    float tmax = -1e30f;
    #pragma unroll
    for (int kb = 0; kb < 4; ++kb)
      #pragma unroll
      for (int r = 0; r < 4; ++r) {
        float val = s[kb][r] * 0.125f;
        if (diag && (kt + kb * 16 + g * 4 + r > qg)) val = -1e30f;
        p[kb][r] = val;
        tmax = fmaxf(tmax, val);
      }
    tmax = fmaxf(tmax, __shfl_xor(tmax, 16));
    tmax = fmaxf(tmax, __shfl_xor(tmax, 32));
    float mnew = fmaxf(mst, tmax);
    float alpha = __expf(mst - mnew);
    float psum = 0.f;
    #pragma unroll
    for (int kb = 0; kb < 4; ++kb)
      #pragma unroll
      for (int r = 0; r < 4; ++r) {
        float e = __expf(p[kb][r] - mnew);
        p[kb][r] = e;
        psum += e;
      }
    psum += __shfl_xor(psum, 16);
    psum += __shfl_xor(psum, 32);
    lsum = lsum * alpha + psum;
    mst = mnew;
    #pragma unroll
    for (int db = 0; db < 4; ++db) {
      ot[db][0] *= alpha; ot[db][1] *= alpha;
      ot[db][2] *= alpha; ot[db][3] *= alpha;
    }

    #pragma unroll
    for (int h = 0; h < 2; ++h) {
      bfx8 pf;
      #pragma unroll
      for (int j = 0; j < 8; ++j)
        pf[j] = (__bf16)p[2 * h + (j >> 2)][j & 3];
      #pragma unroll
      for (int db = 0; db < 4; ++db) {
        us4 lo = *(const us4*)(&Vt[swz(16 * db + c, 32 * h + 4 * g)]);
        us4 hi = *(const us4*)(&Vt[swz(16 * db + c, 32 * h + 16 + 4 * g)]);
        union { us8 u; bfx8 bf; } cv;
        cv.u[0] = lo[0]; cv.u[1] = lo[1]; cv.u[2] = lo[2]; cv.u[3] = lo[3];
        cv.u[4] = hi[0]; cv.u[5] = hi[1]; cv.u[6] = hi[2]; cv.u[7] = hi[3];
        ot[db] = __builtin_amdgcn_mfma_f32_16x16x32_bf16(cv.bf, pf, ot[db], 0, 0, 0);
      }
    }
    __syncthreads();
  }

  if (q0 + c < kS) {
    float inv = 1.0f / lsum;
    u16* op = o + (size_t)(b * kS) * kD + hh * kDH + (size_t)(q0 + c) * kD;
    #pragma unroll
    for (int db = 0; db < 4; ++db)
      #pragma unroll
      for (int r = 0; r < 4; ++r)
        op[16 * db + 4 * g + r] = f2bf(ot[db][r] * inv);
  }
}

// ---------- gathers
__global__ void k_gather_obs(const u16* __restrict__ xf, u16* __restrict__ xo) {
  int r = blockIdx.x;
  int b = r / 960, rr = r % 960;
  int j = rr & 15, blk = rr >> 4;
  int s = blk * kTPB + j + (j == 15 ? 1 : 0);
  const unsigned int* src = (const unsigned int*)(xf + ((size_t)(b * kS + s)) * kD);
  unsigned int* dst = (unsigned int*)(xo + (size_t)r * kD);
  dst[threadIdx.x] = src[threadIdx.x];
  dst[threadIdx.x + 256] = src[threadIdx.x + 256];
}
__global__ void k_gather_act(const u16* __restrict__ xf, u16* __restrict__ xe) {
  int r = blockIdx.x;
  int b = r / 60, rr = r % 60;
  int s = rr * kTPB + (kTPB - 1);
  const unsigned int* src = (const unsigned int*)(xf + ((size_t)(b * kS + s)) * kD);
  unsigned int* dst = (unsigned int*)(xe + (size_t)r * kD);
  dst[threadIdx.x] = src[threadIdx.x];
  dst[threadIdx.x + 256] = src[threadIdx.x + 256];
}

// ---------- ends head (f32 out)
__global__ void k_ends(const u16* __restrict__ t2, const float* __restrict__ he2,
                       const float* __restrict__ be2, float* __restrict__ out) {
  int r = blockIdx.x;
  int t = threadIdx.x;
  float p0 = 0.f, p1 = 0.f;
  for (int j = t; j < kD; j += 256) {
    float xv = bf2f(t2[(size_t)r * kD + j]);
    p0 += xv * he2[j * 2];
    p1 += xv * he2[j * 2 + 1];
  }
  #pragma unroll
  for (int msk = 32; msk; msk >>= 1) { p0 += __shfl_xor(p0, msk); p1 += __shfl_xor(p1, msk); }
  __shared__ float l0[4], l1[4];
  int w = t >> 6;
  if ((t & 63) == 0) { l0[w] = p0; l1[w] = p1; }
  __syncthreads();
  if (t == 0) {
    out[r * 2 + 0] = l0[0] + l0[1] + l0[2] + l0[3] + be2[0];
    out[r * 2 + 1] = l1[0] + l1[1] + l1[2] + l1[3] + be2[1];
  }
}

} // namespace

extern "C" void kernel_launch(void* const* d_in, const int* in_sizes, int n_in,
                              void* d_out, int out_size, void* d_ws, size_t ws_size,
                              hipStream_t stream) {
  const int*   tokens  = (const int*)  d_in[0];
  const float* pos_emb = (const float*)d_in[1];
  const float* emb_obs = (const float*)d_in[2];
  const float* emb_act = (const float*)d_in[3];
  const float* ln1_g = (const float*)d_in[4];
  const float* ln1_b = (const float*)d_in[5];
  const float* wq = (const float*)d_in[6];
  const float* bq = (const float*)d_in[7];
  const float* wk = (const float*)d_in[8];
  const float* bk = (const float*)d_in[9];
  const float* wv = (const float*)d_in[10];
  const float* bv = (const float*)d_in[11];
  const float* wo = (const float*)d_in[12];
  const float* bo = (const float*)d_in[13];
  const float* ln2_g = (const float*)d_in[14];
  const float* ln2_b = (const float*)d_in[15];
  const float* w1 = (const float*)d_in[16];
  const float* b1 = (const float*)d_in[17];
  const float* w2 = (const float*)d_in[18];
  const float* b2 = (const float*)d_in[19];
  const float* lnf_g = (const float*)d_in[20];
  const float* lnf_b = (const float*)d_in[21];
  const float* ho1 = (const float*)d_in[22];
  const float* bo1 = (const float*)d_in[23];
  const float* ho2 = (const float*)d_in[24];
  const float* bo2 = (const float*)d_in[25];
  const float* he1 = (const float*)d_in[26];
  const float* be1 = (const float*)d_in[27];
  const float* he2 = (const float*)d_in[28];
  const float* be2 = (const float*)d_in[29];
  (void)in_sizes; (void)n_in; (void)out_size; (void)ws_size;

  // ---- workspace: ~66.6 MB
  char* ws = (char*)d_ws;
  size_t off = 0;
  auto alloc = [&](size_t bytes) -> char* {
    char* p = ws + off; off += (bytes + 255) & ~(size_t)255; return p;
  };
  u16*   wTbig = (u16*)alloc((size_t)4096 * 1024 * 2);    // 8 MB stacked B^T
  float* x  = (float*)alloc((size_t)kBS * kD * 4);        // 16.71 MB residual
  u16*   h  = (u16*)alloc((size_t)kBS * kD * 2);          // 8.36 MB LN out
  char*  scr = alloc((size_t)kBS * 4096 * 2);             // 33.42 MB
  float* bqkv = (float*)alloc((size_t)4 * 3072 * 4);      // 48 KB packed QKV bias
  const size_t slotB = (size_t)kBS * kD * 2;
  u16* qkv = (u16*)scr;                               // [4080][3072]
  u16* ob  = (u16*)(scr + (size_t)kBS * 3072 * 2);    // [4080][1024]
  u16* mid = (u16*)scr;                               // [4080][4096]
  u16* xf = (u16*)scr;
  u16* xo = (u16*)(scr + slotB);
  u16* t1 = (u16*)(scr + 2 * slotB);
  u16* xe = (u16*)(scr + 3 * slotB);
  u16* t2 = (u16*)(scr + 3 * slotB + (size_t)240 * kD * 2 + 256);

  dim3 tb(32, 8);
  dim3 tg(32, 32);
  k_embed<<<kBS, 256, 0, stream>>>(tokens, pos_emb, emb_obs, emb_act, x);
  k_pack_bias<<<48, 256, 0, stream>>>(bq, bk, bv, bqkv);

  for (int i = 0; i < 4; ++i) {
    const size_t wOff = (size_t)i * kD * kD;
    k_ln<<<kBS, 256, 0, stream>>>(x, ln1_g + i * kD, ln1_b + i * kD, h);

    k_transpose<<<tg, tb, 0, stream>>>(wq + wOff, wTbig, 1024, 1024, 1024);
    k_transpose<<<tg, tb, 0, stream>>>(wk + wOff, wTbig + (size_t)1024 * 1024, 1024, 1024, 1024);
    k_transpose<<<tg, tb, 0, stream>>>(wv + wOff, wTbig + (size_t)2048 * 1024, 1024, 1024, 1024);
    k_gemm<0, 128><<<dim3(32, 24), 256, 0, stream>>>(h, wTbig, bqkv + i * 3072, nullptr, qkv,
                                                     kBS, 3072, 1024, 3072);

    k_attn<<<dim3(16, 64), 256, 0, stream>>>(qkv, qkv + 1024, qkv + 2048, ob, 3072);

    k_transpose<<<tg, tb, 0, stream>>>(wo + wOff, wTbig, 1024, 1024, 1024);
    k_gemm<3, 64><<<dim3(64, 8), 256, 0, stream>>>(ob, wTbig, bo + i * kD, x, x,
                                                   kBS, 1024, 1024, 1024);

    k_ln<<<kBS, 256, 0, stream>>>(x, ln2_g + i * kD, ln2_b + i * kD, h);

    for (int c = 0; c < 4; ++c)
      k_transpose<<<tg, tb, 0, stream>>>(w1 + (size_t)i * kD * 4096 + c * 1024,
                                         wTbig + (size_t)c * 1024 * 1024, 1024, 1024, 4096);
    k_gemm<2, 128><<<dim3(32, 32), 256, 0, stream>>>(h, wTbig, b1 + (size_t)i * 4096, nullptr,
                                                     mid, kBS, 4096, 1024, 4096);
    k_transpose<<<dim3(32, 128), tb, 0, stream>>>(w2 + (size_t)i * 4096 * kD, wTbig,
                                                  4096, 1024, 1024);
    k_gemm<3, 64><<<dim3(64, 8), 256, 0, stream>>>(mid, wTbig, b2 + i * kD, x, x,
                                                   kBS, 1024, 4096, 1024);
  }

  k_ln<<<kBS, 256, 0, stream>>>(x, lnf_g, lnf_b, xf);
  k_gather_obs<<<3840, 256, 0, stream>>>(xf, xo);
  k_gather_act<<<240, 256, 0, stream>>>(xf, xe);

  // obs head
  k_transpose<<<tg, tb, 0, stream>>>(ho1, wTbig, 1024, 1024, 1024);
  k_gemm<1, 64><<<dim3(60, 8), 256, 0, stream>>>(xo, wTbig, bo1, nullptr, t1,
                                                 3840, 1024, 1024, 1024);
  for (int c = 0; c < 4; ++c)
    k_transpose<<<tg, tb, 0, stream>>>(ho2 + c * 1024, wTbig + (size_t)c * 1024 * 1024,
                                       1024, 1024, 4096);
  k_gemm<4, 128><<<dim3(30, 32), 256, 0, stream>>>(t1, wTbig, bo2, nullptr,
                                                   (float*)d_out, 3840, 4096, 1024, 4096);
  // ends head
  k_transpose<<<tg, tb, 0, stream>>>(he1, wTbig, 1024, 1024, 1024);
  k_gemm<1, 64><<<dim3(4, 8), 256, 0, stream>>>(xe, wTbig, be1, nullptr, t2,
                                                240, 1024, 1024, 1024);
  k_ends<<<240, 256, 0, stream>>>(t2, he2, be2, (float*)d_out + (size_t)3840 * 4096);
}

// Round 9
// 1377.311 us; speedup vs baseline: 4.4453x; 1.0588x over previous
//
#include <hip/hip_runtime.h>
#include <hip/hip_bf16.h>
#include <math.h>

namespace {

constexpr int kS = 1020, kD = 1024, kTPB = 17, kDH = 64;
constexpr int kVOBS = 4096, kVACT = 16;
constexpr int kBS = 4080;          // B*S
constexpr float kEPS = 1e-3f;

typedef float f32x4 __attribute__((ext_vector_type(4)));
typedef __bf16 bfx8 __attribute__((ext_vector_type(8)));
typedef unsigned short u16;
typedef u16 us8 __attribute__((ext_vector_type(8)));
typedef u16 us4 __attribute__((ext_vector_type(4)));

__device__ __forceinline__ float bf2f(u16 u) {
  union { unsigned int i; float f; } v; v.i = (unsigned int)u << 16; return v.f;
}
__device__ __forceinline__ u16 f2bf(float f) {
  union { float f; unsigned int i; } v; v.f = f;
  unsigned int r = v.i + 0x7FFFu + ((v.i >> 16) & 1u);
  return (u16)(r >> 16);
}

// ---------- embed
__global__ void k_embed(const int* __restrict__ tokens, const float* __restrict__ pos_emb,
                        const float* __restrict__ emb_obs, const float* __restrict__ emb_act,
                        float* __restrict__ x) {
  int bs = blockIdx.x;
  int s = bs % kS;
  int tk = tokens[bs];
  bool obs = (s % kTPB) < (kTPB - 1);
  const float* e;
  if (obs) { int t2 = tk < kVOBS - 1 ? tk : kVOBS - 1; e = emb_obs + (size_t)t2 * kD; }
  else     { int t2 = tk < kVACT - 1 ? tk : kVACT - 1; e = emb_act + (size_t)t2 * kD; }
  int c = threadIdx.x * 4;
  float4 ev = *(const float4*)(e + c);
  float4 pv = *(const float4*)(pos_emb + (size_t)s * kD + c);
  float4 o; o.x = ev.x + pv.x; o.y = ev.y + pv.y; o.z = ev.z + pv.z; o.w = ev.w + pv.w;
  *(float4*)(x + (size_t)bs * kD + c) = o;
}

// ---------- bias pack (QKV)
__global__ void k_pack_bias(const float* __restrict__ bq, const float* __restrict__ bk,
                            const float* __restrict__ bv, float* __restrict__ bqkv) {
  int idx = blockIdx.x * 256 + threadIdx.x;      // 0..12287
  int l = idx / 3072, rem = idx % 3072;
  int sel = rem >> 10, cc = rem & 1023;
  const float* src = sel == 0 ? bq : (sel == 1 ? bk : bv);
  bqkv[idx] = src[l * kD + cc];
}

// ---------- LayerNorm: f32 in -> bf16 out.
__global__ void k_ln(const float* __restrict__ x, const float* __restrict__ g,
                     const float* __restrict__ b, u16* __restrict__ out) {
  int row = blockIdx.x;
  int t = threadIdx.x;
  const float* xr = x + (size_t)row * kD;
  float4 v = *(const float4*)(xr + t * 4);
  float s1 = v.x + v.y + v.z + v.w;
  float s2 = v.x * v.x + v.y * v.y + v.z * v.z + v.w * v.w;
  #pragma unroll
  for (int m = 32; m; m >>= 1) { s1 += __shfl_xor(s1, m); s2 += __shfl_xor(s2, m); }
  __shared__ float ls1[4], ls2[4];
  int w = t >> 6;
  if ((t & 63) == 0) { ls1[w] = s1; ls2[w] = s2; }
  __syncthreads();
  float S1 = ls1[0] + ls1[1] + ls1[2] + ls1[3];
  float S2 = ls2[0] + ls2[1] + ls2[2] + ls2[3];
  float mean = S1 * (1.0f / kD);
  float var = S2 * (1.0f / kD) - mean * mean;
  float rs = rsqrtf(var + kEPS);
  int c = t * 4;
  float4 gv = *(const float4*)(g + c);
  float4 bv = *(const float4*)(b + c);
  us4 o;
  o[0] = f2bf((v.x - mean) * rs * gv.x + bv.x);
  o[1] = f2bf((v.y - mean) * rs * gv.y + bv.y);
  o[2] = f2bf((v.z - mean) * rs * gv.z + bv.z);
  o[3] = f2bf((v.w - mean) * rs * gv.w + bv.w);
  *(us4*)(out + (size_t)row * kD + c) = o;
}

// ---------- transpose + f32->bf16
__global__ void k_transpose(const float* __restrict__ in, u16* __restrict__ out,
                            int R, int C, int ld) {
  __shared__ float tile[32][33];
  int tx = threadIdx.x, ty = threadIdx.y;
  int c0 = blockIdx.x * 32, r0 = blockIdx.y * 32;
  #pragma unroll
  for (int i = 0; i < 4; ++i)
    tile[ty + i * 8][tx] = in[(size_t)(r0 + ty + i * 8) * ld + c0 + tx];
  __syncthreads();
  #pragma unroll
  for (int i = 0; i < 4; ++i)
    out[(size_t)(c0 + ty + i * 8) * R + r0 + tx] = f2bf(tile[tx][ty + i * 8]);
}

// ---------- MFMA GEMM, 2-phase double-buffered global_load_lds pipeline.
// out[M][ldo] = A[M][K](bf16) * Bt[N][K](bf16)^T + bias(f32).
// BM x 128 tile, BK=32; LDS linear 64B rows, 16B-chunk XOR swizzle
// (slot = chunk ^ ((row>>1)&3)) on BOTH global-source and LDS-read sides.
// Pipeline: stage(t+1) issued BEFORE compute(t); ONE barrier per k-step
// (prev barrier protects WAR on buf^1; vmcnt(0) inside syncthreads drains stage).
// EPI: 0 bf16, 1 bf16 relu, 2 bf16 gelu, 3 f32 resid+val, 4 f32 store
template <int EPI, int BM>
__global__ void __launch_bounds__(256)
k_gemm(const u16* __restrict__ A, const u16* __restrict__ Bt, const float* __restrict__ bias,
       const float* __restrict__ resid, void* __restrict__ out, int M, int N, int K, int ldo) {
  constexpr int MFRAG = BM / 32;
  __shared__ alignas(16) u16 As[2][BM * 32];    // [buf][row*32], linear 64B rows
  __shared__ alignas(16) u16 Bs[2][128 * 32];
  int tid = threadIdx.x;
  int m0 = blockIdx.x * BM, n0 = blockIdx.y * 128;   // natural order (L3-fit regime)
  int lane = tid & 63, wv = tid >> 6;
  int wm = wv >> 1, wn = wv & 1;
  f32x4 acc[MFRAG][4] = {};

  auto stage = [&](int buf, int k0) {
    #pragma unroll
    for (int n = 0; n < BM / 64; ++n) {      // A: BM rows x 4 chunks(16B)
      int u = n * 256 + tid;
      int r = u >> 2, ch = u & 3;
      int gr = m0 + r; if (gr >= M) gr = M - 1;   // clamp: dup rows never stored
      int cg = ch ^ ((r >> 1) & 3);
      const u16* src = A + (size_t)gr * K + k0 + cg * 8;
      __builtin_amdgcn_global_load_lds(
          (const __attribute__((address_space(1))) unsigned int*)src,
          (__attribute__((address_space(3))) unsigned int*)&As[buf][(n * 256 + wv * 64) * 8],
          16, 0, 0);
    }
    #pragma unroll
    for (int n = 0; n < 2; ++n) {            // B: 128 rows x 4 chunks
      int u = n * 256 + tid;
      int r = u >> 2, ch = u & 3;
      int cg = ch ^ ((r >> 1) & 3);
      const u16* src = Bt + (size_t)(n0 + r) * K + k0 + cg * 8;
      __builtin_amdgcn_global_load_lds(
          (const __attribute__((address_space(1))) unsigned int*)src,
          (__attribute__((address_space(3))) unsigned int*)&Bs[buf][(n * 256 + wv * 64) * 8],
          16, 0, 0);
    }
  };

  stage(0, 0);
  __syncthreads();
  const int nk = K >> 5;
  for (int t = 0; t < nk; ++t) {
    int cur = t & 1;
    if (t + 1 < nk) stage(cur ^ 1, (t + 1) << 5);   // prefetch flies under compute

    bfx8 af[MFRAG], bfr[4];
    int ch = lane >> 4;                      // logical k-chunk for this lane
    #pragma unroll
    for (int mf = 0; mf < MFRAG; ++mf) {
      int row = wm * (BM / 2) + mf * 16 + (lane & 15);
      af[mf] = *(const bfx8*)(&As[cur][row * 32 + ((ch ^ ((row >> 1) & 3)) << 3)]);
    }
    #pragma unroll
    for (int nf = 0; nf < 4; ++nf) {
      int row = wn * 64 + nf * 16 + (lane & 15);
      bfr[nf] = *(const bfx8*)(&Bs[cur][row * 32 + ((ch ^ ((row >> 1) & 3)) << 3)]);
    }
    #pragma unroll
    for (int mf = 0; mf < MFRAG; ++mf)
      #pragma unroll
      for (int nf = 0; nf < 4; ++nf)
        acc[mf][nf] = __builtin_amdgcn_mfma_f32_16x16x32_bf16(af[mf], bfr[nf], acc[mf][nf], 0, 0, 0);
    __syncthreads();   // drains stage loads (vmcnt 0) + protects buf swap
  }

  #pragma unroll
  for (int mf = 0; mf < MFRAG; ++mf) {
    #pragma unroll
    for (int nf = 0; nf < 4; ++nf) {
      int gcol = n0 + wn * 64 + nf * 16 + (lane & 15);
      float bv = bias ? bias[gcol] : 0.0f;
      #pragma unroll
      for (int r = 0; r < 4; ++r) {
        int grow = m0 + wm * (BM / 2) + mf * 16 + (lane >> 4) * 4 + r;
        if (grow >= M) continue;
        float val = acc[mf][nf][r] + bv;
        size_t off2 = (size_t)grow * ldo + gcol;
        if (EPI == 0) {
          ((u16*)out)[off2] = f2bf(val);
        } else if (EPI == 1) {
          ((u16*)out)[off2] = f2bf(val > 0.f ? val : 0.f);
        } else if (EPI == 2) {
          ((u16*)out)[off2] = f2bf(0.5f * val * (1.f + erff(val * 0.70710678118654752440f)));
        } else if (EPI == 3) {
          ((float*)out)[off2] = resid[off2] + val;
        } else {
          ((float*)out)[off2] = val;
        }
      }
    }
  }
}

// ---------- MFMA flash attention (swapped-operand). q/k/v row stride = ldin.
__device__ __forceinline__ int swz(int row, int colu16) {
  return (row * 64 + colu16) ^ ((row & 7) << 3) ^ ((row & 24) << 1);
}

__global__ void __launch_bounds__(256)
k_attn(const u16* __restrict__ q, const u16* __restrict__ k, const u16* __restrict__ v,
       u16* __restrict__ o, int ldin) {
  __shared__ u16 Kl[64 * 64];
  __shared__ u16 Vt[64 * 64];
  const int qb = blockIdx.x * 64;
  const int bh = blockIdx.y;
  const int b = bh >> 4, hh = bh & 15;
  const int tid = threadIdx.x;
  const int lane = tid & 63, w = tid >> 6;
  const int g = lane >> 4, c = lane & 15;
  const int q0 = qb + w * 16;
  const size_t base = (size_t)(b * kS) * ldin + hh * kDH;

  bfx8 qf0, qf1;
  {
    int qr = q0 + c; if (qr >= kS) qr = kS - 1;
    const u16* qp = q + base + (size_t)qr * ldin + g * 8;
    qf0 = *(const bfx8*)(qp);
    qf1 = *(const bfx8*)(qp + 32);
  }

  float mst = -1e30f, lsum = 0.f;
  f32x4 ot[4] = {};

  const int ntiles = blockIdx.x + 1;
  for (int t = 0; t < ntiles; ++t) {
    const int kt = t * 64;
    {
      int kr = tid >> 2, ds2 = (tid & 3) * 16;
      int kg = kt + kr; if (kg >= kS) kg = kS - 1;
      const u16* kp = k + base + (size_t)kg * ldin + ds2;
      us8 a0 = *(const us8*)(kp);
      us8 a1 = *(const us8*)(kp + 8);
      *(us8*)(&Kl[swz(kr, ds2)]) = a0;
      *(us8*)(&Kl[swz(kr, ds2 + 8)]) = a1;
      const u16* vp = v + base + (size_t)kg * ldin + ds2;
      us8 b0 = *(const us8*)(vp);
      us8 b1 = *(const us8*)(vp + 8);
      #pragma unroll
      for (int i2 = 0; i2 < 8; ++i2) Vt[swz(ds2 + i2, kr)] = b0[i2];
      #pragma unroll
      for (int i2 = 0; i2 < 8; ++i2) Vt[swz(ds2 + 8 + i2, kr)] = b1[i2];
    }
    __syncthreads();

    f32x4 s[4];
    #pragma unroll
    for (int kb = 0; kb < 4; ++kb) {
      bfx8 kf0 = *(const bfx8*)(&Kl[swz(kb * 16 + c, g * 8)]);
      bfx8 kf1 = *(const bfx8*)(&Kl[swz(kb * 16 + c, g * 8 + 32)]);
      f32x4 acc = {};
      acc = __builtin_amdgcn_mfma_f32_16x16x32_bf16(kf0, qf0, acc, 0, 0, 0);
      acc = __builtin_amdgcn_mfma_f32_16x16x32_bf16(kf1, qf1, acc, 0, 0, 0);
      s[kb] = acc;
    }

    const int qg = q0 + c;
    const bool diag = (kt + 63 > q0);
    float p[4][4];
    float tmax = -1e30f;
    #pragma unroll
    for (int kb = 0; kb < 4; ++kb)
      #pragma unroll
      for (int r = 0; r < 4; ++r) {
        float val = s[kb][r] * 0.125f;
        if (diag && (kt + kb * 16 + g * 4 + r > qg)) val = -1e30f;
        p[kb][r] = val;
        tmax = fmaxf(tmax, val);
      }
    tmax = fmaxf(tmax, __shfl_xor(tmax, 16));
    tmax = fmaxf(tmax, __shfl_xor(tmax, 32));
    float mnew = fmaxf(mst, tmax);
    float alpha = __expf(mst - mnew);
    float psum = 0.f;
    #pragma unroll
    for (int kb = 0; kb < 4; ++kb)
      #pragma unroll
      for (int r = 0; r < 4; ++r) {
        float e = __expf(p[kb][r] - mnew);
        p[kb][r] = e;
        psum += e;
      }
    psum += __shfl_xor(psum, 16);
    psum += __shfl_xor(psum, 32);
    lsum = lsum * alpha + psum;
    mst = mnew;
    #pragma unroll
    for (int db = 0; db < 4; ++db) {
      ot[db][0] *= alpha; ot[db][1] *= alpha;
      ot[db][2] *= alpha; ot[db][3] *= alpha;
    }

    #pragma unroll
    for (int h = 0; h < 2; ++h) {
      bfx8 pf;
      #pragma unroll
      for (int j = 0; j < 8; ++j)
        pf[j] = (__bf16)p[2 * h + (j >> 2)][j & 3];
      #pragma unroll
      for (int db = 0; db < 4; ++db) {
        us4 lo = *(const us4*)(&Vt[swz(16 * db + c, 32 * h + 4 * g)]);
        us4 hi = *(const us4*)(&Vt[swz(16 * db + c, 32 * h + 16 + 4 * g)]);
        union { us8 u; bfx8 bf; } cv;
        cv.u[0] = lo[0]; cv.u[1] = lo[1]; cv.u[2] = lo[2]; cv.u[3] = lo[3];
        cv.u[4] = hi[0]; cv.u[5] = hi[1]; cv.u[6] = hi[2]; cv.u[7] = hi[3];
        ot[db] = __builtin_amdgcn_mfma_f32_16x16x32_bf16(cv.bf, pf, ot[db], 0, 0, 0);
      }
    }
    __syncthreads();
  }

  if (q0 + c < kS) {
    float inv = 1.0f / lsum;
    u16* op = o + (size_t)(b * kS) * kD + hh * kDH + (size_t)(q0 + c) * kD;
    #pragma unroll
    for (int db = 0; db < 4; ++db)
      #pragma unroll
      for (int r = 0; r < 4; ++r)
        op[16 * db + 4 * g + r] = f2bf(ot[db][r] * inv);
  }
}

// ---------- gathers
__global__ void k_gather_obs(const u16* __restrict__ xf, u16* __restrict__ xo) {
  int r = blockIdx.x;
  int b = r / 960, rr = r % 960;
  int j = rr & 15, blk = rr >> 4;
  int s = blk * kTPB + j + (j == 15 ? 1 : 0);
  const unsigned int* src = (const unsigned int*)(xf + ((size_t)(b * kS + s)) * kD);
  unsigned int* dst = (unsigned int*)(xo + (size_t)r * kD);
  dst[threadIdx.x] = src[threadIdx.x];
  dst[threadIdx.x + 256] = src[threadIdx.x + 256];
}
__global__ void k_gather_act(const u16* __restrict__ xf, u16* __restrict__ xe) {
  int r = blockIdx.x;
  int b = r / 60, rr = r % 60;
  int s = rr * kTPB + (kTPB - 1);
  const unsigned int* src = (const unsigned int*)(xf + ((size_t)(b * kS + s)) * kD);
  unsigned int* dst = (unsigned int*)(xe + (size_t)r * kD);
  dst[threadIdx.x] = src[threadIdx.x];
  dst[threadIdx.x + 256] = src[threadIdx.x + 256];
}

// ---------- ends head (f32 out)
__global__ void k_ends(const u16* __restrict__ t2, const float* __restrict__ he2,
                       const float* __restrict__ be2, float* __restrict__ out) {
  int r = blockIdx.x;
  int t = threadIdx.x;
  float p0 = 0.f, p1 = 0.f;
  for (int j = t; j < kD; j += 256) {
    float xv = bf2f(t2[(size_t)r * kD + j]);
    p0 += xv * he2[j * 2];
    p1 += xv * he2[j * 2 + 1];
  }
  #pragma unroll
  for (int msk = 32; msk; msk >>= 1) { p0 += __shfl_xor(p0, msk); p1 += __shfl_xor(p1, msk); }
  __shared__ float l0[4], l1[4];
  int w = t >> 6;
  if ((t & 63) == 0) { l0[w] = p0; l1[w] = p1; }
  __syncthreads();
  if (t == 0) {
    out[r * 2 + 0] = l0[0] + l0[1] + l0[2] + l0[3] + be2[0];
    out[r * 2 + 1] = l1[0] + l1[1] + l1[2] + l1[3] + be2[1];
  }
}

} // namespace

extern "C" void kernel_launch(void* const* d_in, const int* in_sizes, int n_in,
                              void* d_out, int out_size, void* d_ws, size_t ws_size,
                              hipStream_t stream) {
  const int*   tokens  = (const int*)  d_in[0];
  const float* pos_emb = (const float*)d_in[1];
  const float* emb_obs = (const float*)d_in[2];
  const float* emb_act = (const float*)d_in[3];
  const float* ln1_g = (const float*)d_in[4];
  const float* ln1_b = (const float*)d_in[5];
  const float* wq = (const float*)d_in[6];
  const float* bq = (const float*)d_in[7];
  const float* wk = (const float*)d_in[8];
  const float* bk = (const float*)d_in[9];
  const float* wv = (const float*)d_in[10];
  const float* bv = (const float*)d_in[11];
  const float* wo = (const float*)d_in[12];
  const float* bo = (const float*)d_in[13];
  const float* ln2_g = (const float*)d_in[14];
  const float* ln2_b = (const float*)d_in[15];
  const float* w1 = (const float*)d_in[16];
  const float* b1 = (const float*)d_in[17];
  const float* w2 = (const float*)d_in[18];
  const float* b2 = (const float*)d_in[19];
  const float* lnf_g = (const float*)d_in[20];
  const float* lnf_b = (const float*)d_in[21];
  const float* ho1 = (const float*)d_in[22];
  const float* bo1 = (const float*)d_in[23];
  const float* ho2 = (const float*)d_in[24];
  const float* bo2 = (const float*)d_in[25];
  const float* he1 = (const float*)d_in[26];
  const float* be1 = (const float*)d_in[27];
  const float* he2 = (const float*)d_in[28];
  const float* be2 = (const float*)d_in[29];
  (void)in_sizes; (void)n_in; (void)out_size; (void)ws_size;

  // ---- workspace: ~66.6 MB
  char* ws = (char*)d_ws;
  size_t off = 0;
  auto alloc = [&](size_t bytes) -> char* {
    char* p = ws + off; off += (bytes + 255) & ~(size_t)255; return p;
  };
  u16*   wTbig = (u16*)alloc((size_t)4096 * 1024 * 2);    // 8 MB stacked B^T
  float* x  = (float*)alloc((size_t)kBS * kD * 4);        // 16.71 MB residual
  u16*   h  = (u16*)alloc((size_t)kBS * kD * 2);          // 8.36 MB LN out
  char*  scr = alloc((size_t)kBS * 4096 * 2);             // 33.42 MB
  float* bqkv = (float*)alloc((size_t)4 * 3072 * 4);      // 48 KB packed QKV bias
  const size_t slotB = (size_t)kBS * kD * 2;
  u16* qkv = (u16*)scr;                               // [4080][3072]
  u16* ob  = (u16*)(scr + (size_t)kBS * 3072 * 2);    // [4080][1024]
  u16* mid = (u16*)scr;                               // [4080][4096]
  u16* xf = (u16*)scr;
  u16* xo = (u16*)(scr + slotB);
  u16* t1 = (u16*)(scr + 2 * slotB);
  u16* xe = (u16*)(scr + 3 * slotB);
  u16* t2 = (u16*)(scr + 3 * slotB + (size_t)240 * kD * 2 + 256);

  dim3 tb(32, 8);
  dim3 tg(32, 32);
  k_embed<<<kBS, 256, 0, stream>>>(tokens, pos_emb, emb_obs, emb_act, x);
  k_pack_bias<<<48, 256, 0, stream>>>(bq, bk, bv, bqkv);

  for (int i = 0; i < 4; ++i) {
    const size_t wOff = (size_t)i * kD * kD;
    k_ln<<<kBS, 256, 0, stream>>>(x, ln1_g + i * kD, ln1_b + i * kD, h);

    k_transpose<<<tg, tb, 0, stream>>>(wq + wOff, wTbig, 1024, 1024, 1024);
    k_transpose<<<tg, tb, 0, stream>>>(wk + wOff, wTbig + (size_t)1024 * 1024, 1024, 1024, 1024);
    k_transpose<<<tg, tb, 0, stream>>>(wv + wOff, wTbig + (size_t)2048 * 1024, 1024, 1024, 1024);
    k_gemm<0, 128><<<dim3(32, 24), 256, 0, stream>>>(h, wTbig, bqkv + i * 3072, nullptr, qkv,
                                                     kBS, 3072, 1024, 3072);

    k_attn<<<dim3(16, 64), 256, 0, stream>>>(qkv, qkv + 1024, qkv + 2048, ob, 3072);

    k_transpose<<<tg, tb, 0, stream>>>(wo + wOff, wTbig, 1024, 1024, 1024);
    k_gemm<3, 64><<<dim3(64, 8), 256, 0, stream>>>(ob, wTbig, bo + i * kD, x, x,
                                                   kBS, 1024, 1024, 1024);

    k_ln<<<kBS, 256, 0, stream>>>(x, ln2_g + i * kD, ln2_b + i * kD, h);

    for (int c = 0; c < 4; ++c)
      k_transpose<<<tg, tb, 0, stream>>>(w1 + (size_t)i * kD * 4096 + c * 1024,
                                         wTbig + (size_t)c * 1024 * 1024, 1024, 1024, 4096);
    k_gemm<2, 128><<<dim3(32, 32), 256, 0, stream>>>(h, wTbig, b1 + (size_t)i * 4096, nullptr,
                                                     mid, kBS, 4096, 1024, 4096);
    k_transpose<<<dim3(32, 128), tb, 0, stream>>>(w2 + (size_t)i * 4096 * kD, wTbig,
                                                  4096, 1024, 1024);
    k_gemm<3, 64><<<dim3(64, 8), 256, 0, stream>>>(mid, wTbig, b2 + i * kD, x, x,
                                                   kBS, 1024, 4096, 1024);
  }

  k_ln<<<kBS, 256, 0, stream>>>(x, lnf_g, lnf_b, xf);
  k_gather_obs<<<3840, 256, 0, stream>>>(xf, xo);
  k_gather_act<<<240, 256, 0, stream>>>(xf, xe);

  // obs head
  k_transpose<<<tg, tb, 0, stream>>>(ho1, wTbig, 1024, 1024, 1024);
  k_gemm<1, 64><<<dim3(60, 8), 256, 0, stream>>>(xo, wTbig, bo1, nullptr, t1,
                                                 3840, 1024, 1024, 1024);
  for (int c = 0; c < 4; ++c)
    k_transpose<<<tg, tb, 0, stream>>>(ho2 + c * 1024, wTbig + (size_t)c * 1024 * 1024,
                                       1024, 1024, 4096);
  k_gemm<4, 128><<<dim3(30, 32), 256, 0, stream>>>(t1, wTbig, bo2, nullptr,
                                                   (float*)d_out, 3840, 4096, 1024, 4096);
  // ends head
  k_transpose<<<tg, tb, 0, stream>>>(he1, wTbig, 1024, 1024, 1024);
  k_gemm<1, 64><<<dim3(4, 8), 256, 0, stream>>>(xe, wTbig, be1, nullptr, t2,
                                                240, 1024, 1024, 1024);
  k_ends<<<240, 256, 0, stream>>>(t2, he2, be2, (float*)d_out + (size_t)3840 * 4096);
}

// Round 10
// 1282.936 us; speedup vs baseline: 4.7724x; 1.0736x over previous
//
#include <hip/hip_runtime.h>
#include <hip/hip_bf16.h>
#include <math.h>

namespace {

constexpr int kS = 1020, kD = 1024, kTPB = 17, kDH = 64;
constexpr int kVOBS = 4096, kVACT = 16;
constexpr int kBS = 4080;          // B*S
constexpr float kEPS = 1e-3f;

typedef float f32x4 __attribute__((ext_vector_type(4)));
typedef __bf16 bfx8 __attribute__((ext_vector_type(8)));
typedef unsigned short u16;
typedef u16 us8 __attribute__((ext_vector_type(8)));
typedef u16 us4 __attribute__((ext_vector_type(4)));

__device__ __forceinline__ float bf2f(u16 u) {
  union { unsigned int i; float f; } v; v.i = (unsigned int)u << 16; return v.f;
}
__device__ __forceinline__ u16 f2bf(float f) {
  union { float f; unsigned int i; } v; v.f = f;
  unsigned int r = v.i + 0x7FFFu + ((v.i >> 16) & 1u);
  return (u16)(r >> 16);
}

// ---------- embed
__global__ void k_embed(const int* __restrict__ tokens, const float* __restrict__ pos_emb,
                        const float* __restrict__ emb_obs, const float* __restrict__ emb_act,
                        float* __restrict__ x) {
  int bs = blockIdx.x;
  int s = bs % kS;
  int tk = tokens[bs];
  bool obs = (s % kTPB) < (kTPB - 1);
  const float* e;
  if (obs) { int t2 = tk < kVOBS - 1 ? tk : kVOBS - 1; e = emb_obs + (size_t)t2 * kD; }
  else     { int t2 = tk < kVACT - 1 ? tk : kVACT - 1; e = emb_act + (size_t)t2 * kD; }
  int c = threadIdx.x * 4;
  float4 ev = *(const float4*)(e + c);
  float4 pv = *(const float4*)(pos_emb + (size_t)s * kD + c);
  float4 o; o.x = ev.x + pv.x; o.y = ev.y + pv.y; o.z = ev.z + pv.z; o.w = ev.w + pv.w;
  *(float4*)(x + (size_t)bs * kD + c) = o;
}

// ---------- bias pack (QKV)
__global__ void k_pack_bias(const float* __restrict__ bq, const float* __restrict__ bk,
                            const float* __restrict__ bv, float* __restrict__ bqkv) {
  int idx = blockIdx.x * 256 + threadIdx.x;      // 0..12287
  int l = idx / 3072, rem = idx % 3072;
  int sel = rem >> 10, cc = rem & 1023;
  const float* src = sel == 0 ? bq : (sel == 1 ? bk : bv);
  bqkv[idx] = src[l * kD + cc];
}

// ---------- LayerNorm: f32 in -> bf16 out.
__global__ void k_ln(const float* __restrict__ x, const float* __restrict__ g,
                     const float* __restrict__ b, u16* __restrict__ out) {
  int row = blockIdx.x;
  int t = threadIdx.x;
  const float* xr = x + (size_t)row * kD;
  float4 v = *(const float4*)(xr + t * 4);
  float s1 = v.x + v.y + v.z + v.w;
  float s2 = v.x * v.x + v.y * v.y + v.z * v.z + v.w * v.w;
  #pragma unroll
  for (int m = 32; m; m >>= 1) { s1 += __shfl_xor(s1, m); s2 += __shfl_xor(s2, m); }
  __shared__ float ls1[4], ls2[4];
  int w = t >> 6;
  if ((t & 63) == 0) { ls1[w] = s1; ls2[w] = s2; }
  __syncthreads();
  float S1 = ls1[0] + ls1[1] + ls1[2] + ls1[3];
  float S2 = ls2[0] + ls2[1] + ls2[2] + ls2[3];
  float mean = S1 * (1.0f / kD);
  float var = S2 * (1.0f / kD) - mean * mean;
  float rs = rsqrtf(var + kEPS);
  int c = t * 4;
  float4 gv = *(const float4*)(g + c);
  float4 bv = *(const float4*)(b + c);
  us4 o;
  o[0] = f2bf((v.x - mean) * rs * gv.x + bv.x);
  o[1] = f2bf((v.y - mean) * rs * gv.y + bv.y);
  o[2] = f2bf((v.z - mean) * rs * gv.z + bv.z);
  o[3] = f2bf((v.w - mean) * rs * gv.w + bv.w);
  *(us4*)(out + (size_t)row * kD + c) = o;
}

// ---------- transpose + f32->bf16 (single)
__global__ void k_transpose(const float* __restrict__ in, u16* __restrict__ out,
                            int R, int C, int ld) {
  __shared__ float tile[32][33];
  int tx = threadIdx.x, ty = threadIdx.y;
  int c0 = blockIdx.x * 32, r0 = blockIdx.y * 32;
  #pragma unroll
  for (int i = 0; i < 4; ++i)
    tile[ty + i * 8][tx] = in[(size_t)(r0 + ty + i * 8) * ld + c0 + tx];
  __syncthreads();
  #pragma unroll
  for (int i = 0; i < 4; ++i)
    out[(size_t)(c0 + ty + i * 8) * R + r0 + tx] = f2bf(tile[tx][ty + i * 8]);
}

// ---------- batched 1024x1024 transpose (4 segments via blockIdx.z)
struct T4 {
  const float* in0; const float* in1; const float* in2; const float* in3;
  u16* out0; u16* out1; u16* out2; u16* out3;
  int ld;
};
__global__ void k_transpose4(T4 sp) {
  const float* in; u16* out;
  switch (blockIdx.z) {
    case 0:  in = sp.in0; out = sp.out0; break;
    case 1:  in = sp.in1; out = sp.out1; break;
    case 2:  in = sp.in2; out = sp.out2; break;
    default: in = sp.in3; out = sp.out3; break;
  }
  __shared__ float tile[32][33];
  int tx = threadIdx.x, ty = threadIdx.y;
  int c0 = blockIdx.x * 32, r0 = blockIdx.y * 32;
  #pragma unroll
  for (int i = 0; i < 4; ++i)
    tile[ty + i * 8][tx] = in[(size_t)(r0 + ty + i * 8) * sp.ld + c0 + tx];
  __syncthreads();
  #pragma unroll
  for (int i = 0; i < 4; ++i)
    out[(size_t)(c0 + ty + i * 8) * 1024 + r0 + tx] = f2bf(tile[tx][ty + i * 8]);
}

// ---------- MFMA GEMM: 3-buffer counted-vmcnt pipeline (T3/T4 mechanism).
// out[M][ldo] = A[M][K](bf16) * Bt[N][K](bf16)^T + bias(f32).
// BM x 128 tile, BK=32; LDS linear 64B rows, 16B-chunk XOR swizzle
// (slot = chunk ^ ((row>>1)&3)) on BOTH global-source and LDS-read sides.
// Per k-step: wait vmcnt(2*LOADS) [oldest tile done, FIFO retire] -> raw barrier
// -> ds_read frags -> lgkmcnt(0) -> raw barrier -> restage(t+3) -> MFMA.
// vmcnt never drained to 0 in steady state.
// EPI: 0 bf16, 1 bf16 relu, 2 bf16 gelu, 3 f32 resid+val, 4 f32 store
template <int EPI, int BM>
__global__ void __launch_bounds__(256)
k_gemm(const u16* __restrict__ A, const u16* __restrict__ Bt, const float* __restrict__ bias,
       const float* __restrict__ resid, void* __restrict__ out, int M, int N, int K, int ldo) {
  constexpr int MFRAG = BM / 32;
  constexpr int LOADS = BM / 64 + 2;           // per-thread gload_lds per tile
  __shared__ alignas(16) u16 As[3][BM * 32];   // linear 64B rows
  __shared__ alignas(16) u16 Bs[3][128 * 32];
  int tid = threadIdx.x;
  int m0 = blockIdx.x * BM, n0 = blockIdx.y * 128;  // natural order (L3-fit regime)
  int lane = tid & 63, wv = tid >> 6;
  int wm = wv >> 1, wn = wv & 1;
  f32x4 acc[MFRAG][4] = {};

  auto stage = [&](int buf, int k0) {
    #pragma unroll
    for (int n = 0; n < BM / 64; ++n) {        // A: BM rows x 4 chunks(16B)
      int u = n * 256 + tid;
      int r = u >> 2, ch = u & 3;
      int gr = m0 + r; if (gr >= M) gr = M - 1;     // clamp: dup rows never stored
      int cg = ch ^ ((r >> 1) & 3);
      const u16* src = A + (size_t)gr * K + k0 + cg * 8;
      __builtin_amdgcn_global_load_lds(
          (const __attribute__((address_space(1))) unsigned int*)src,
          (__attribute__((address_space(3))) unsigned int*)&As[buf][(n * 256 + wv * 64) * 8],
          16, 0, 0);
    }
    #pragma unroll
    for (int n = 0; n < 2; ++n) {              // B: 128 rows x 4 chunks
      int u = n * 256 + tid;
      int r = u >> 2, ch = u & 3;
      int cg = ch ^ ((r >> 1) & 3);
      const u16* src = Bt + (size_t)(n0 + r) * K + k0 + cg * 8;
      __builtin_amdgcn_global_load_lds(
          (const __attribute__((address_space(1))) unsigned int*)src,
          (__attribute__((address_space(3))) unsigned int*)&Bs[buf][(n * 256 + wv * 64) * 8],
          16, 0, 0);
    }
  };

  const int nk = K >> 5;                       // all call sites: nk >= 32
  stage(0, 0);
  stage(1, 32);
  stage(2, 64);
  for (int t = 0; t < nk; ++t) {
    int cur = t % 3;
    // wait until tile t's loads retired (loads retire FIFO per vmcnt semantics)
    if (t + 2 < nk)
      asm volatile("s_waitcnt vmcnt(%0)" :: "i"(2 * LOADS) : "memory");
    else if (t + 1 < nk)
      asm volatile("s_waitcnt vmcnt(%0)" :: "i"(LOADS) : "memory");
    else
      asm volatile("s_waitcnt vmcnt(0)" ::: "memory");
    __builtin_amdgcn_s_barrier();
    __builtin_amdgcn_sched_barrier(0);

    bfx8 af[MFRAG], bfr[4];
    int ch = lane >> 4;                        // logical k-chunk for this lane
    #pragma unroll
    for (int mf = 0; mf < MFRAG; ++mf) {
      int row = wm * (BM / 2) + mf * 16 + (lane & 15);
      af[mf] = *(const bfx8*)(&As[cur][row * 32 + ((ch ^ ((row >> 1) & 3)) << 3)]);
    }
    #pragma unroll
    for (int nf = 0; nf < 4; ++nf) {
      int row = wn * 64 + nf * 16 + (lane & 15);
      bfr[nf] = *(const bfx8*)(&Bs[cur][row * 32 + ((ch ^ ((row >> 1) & 3)) << 3)]);
    }
    // all LDS reads complete before anyone overwrites this buffer
    asm volatile("s_waitcnt lgkmcnt(0)" ::: "memory");
    __builtin_amdgcn_s_barrier();
    __builtin_amdgcn_sched_barrier(0);
    if (t + 3 < nk) stage(cur, (t + 3) << 5);  // restage flies under MFMA

    #pragma unroll
    for (int mf = 0; mf < MFRAG; ++mf)
      #pragma unroll
      for (int nf = 0; nf < 4; ++nf)
        acc[mf][nf] = __builtin_amdgcn_mfma_f32_16x16x32_bf16(af[mf], bfr[nf], acc[mf][nf], 0, 0, 0);
  }

  #pragma unroll
  for (int mf = 0; mf < MFRAG; ++mf) {
    #pragma unroll
    for (int nf = 0; nf < 4; ++nf) {
      int gcol = n0 + wn * 64 + nf * 16 + (lane & 15);
      float bv = bias ? bias[gcol] : 0.0f;
      #pragma unroll
      for (int r = 0; r < 4; ++r) {
        int grow = m0 + wm * (BM / 2) + mf * 16 + (lane >> 4) * 4 + r;
        if (grow >= M) continue;
        float val = acc[mf][nf][r] + bv;
        size_t off2 = (size_t)grow * ldo + gcol;
        if (EPI == 0) {
          ((u16*)out)[off2] = f2bf(val);
        } else if (EPI == 1) {
          ((u16*)out)[off2] = f2bf(val > 0.f ? val : 0.f);
        } else if (EPI == 2) {
          ((u16*)out)[off2] = f2bf(0.5f * val * (1.f + erff(val * 0.70710678118654752440f)));
        } else if (EPI == 3) {
          ((float*)out)[off2] = resid[off2] + val;
        } else {
          ((float*)out)[off2] = val;
        }
      }
    }
  }
}

// ---------- MFMA flash attention (swapped-operand). q/k/v row stride = ldin.
__device__ __forceinline__ int swz(int row, int colu16) {
  return (row * 64 + colu16) ^ ((row & 7) << 3) ^ ((row & 24) << 1);
}

__global__ void __launch_bounds__(256)
k_attn(const u16* __restrict__ q, const u16* __restrict__ k, const u16* __restrict__ v,
       u16* __restrict__ o, int ldin) {
  __shared__ u16 Kl[64 * 64];
  __shared__ u16 Vt[64 * 64];
  const int qb = blockIdx.x * 64;
  const int bh = blockIdx.y;
  const int b = bh >> 4, hh = bh & 15;
  const int tid = threadIdx.x;
  const int lane = tid & 63, w = tid >> 6;
  const int g = lane >> 4, c = lane & 15;
  const int q0 = qb + w * 16;
  const size_t base = (size_t)(b * kS) * ldin + hh * kDH;

  bfx8 qf0, qf1;
  {
    int qr = q0 + c; if (qr >= kS) qr = kS - 1;
    const u16* qp = q + base + (size_t)qr * ldin + g * 8;
    qf0 = *(const bfx8*)(qp);
    qf1 = *(const bfx8*)(qp + 32);
  }

  float mst = -1e30f, lsum = 0.f;
  f32x4 ot[4] = {};

  const int ntiles = blockIdx.x + 1;
  for (int t = 0; t < ntiles; ++t) {
    const int kt = t * 64;
    {
      int kr = tid >> 2, ds2 = (tid & 3) * 16;
      int kg = kt + kr; if (kg >= kS) kg = kS - 1;
      const u16* kp = k + base + (size_t)kg * ldin + ds2;
      us8 a0 = *(const us8*)(kp);
      us8 a1 = *(const us8*)(kp + 8);
      *(us8*)(&Kl[swz(kr, ds2)]) = a0;
      *(us8*)(&Kl[swz(kr, ds2 + 8)]) = a1;
      const u16* vp = v + base + (size_t)kg * ldin + ds2;
      us8 b0 = *(const us8*)(vp);
      us8 b1 = *(const us8*)(vp + 8);
      #pragma unroll
      for (int i2 = 0; i2 < 8; ++i2) Vt[swz(ds2 + i2, kr)] = b0[i2];
      #pragma unroll
      for (int i2 = 0; i2 < 8; ++i2) Vt[swz(ds2 + 8 + i2, kr)] = b1[i2];
    }
    __syncthreads();

    f32x4 s[4];
    #pragma unroll
    for (int kb = 0; kb < 4; ++kb) {
      bfx8 kf0 = *(const bfx8*)(&Kl[swz(kb * 16 + c, g * 8)]);
      bfx8 kf1 = *(const bfx8*)(&Kl[swz(kb * 16 + c, g * 8 + 32)]);
      f32x4 acc = {};
      acc = __builtin_amdgcn_mfma_f32_16x16x32_bf16(kf0, qf0, acc, 0, 0, 0);
      acc = __builtin_amdgcn_mfma_f32_16x16x32_bf16(kf1, qf1, acc, 0, 0, 0);
      s[kb] = acc;
    }

    const int qg = q0 + c;
    const bool diag = (kt + 63 > q0);
    float p[4][4];
    float tmax = -1e30f;
    #pragma unroll
    for (int kb = 0; kb < 4; ++kb)
      #pragma unroll
      for (int r = 0; r < 4; ++r) {
        float val = s[kb][r] * 0.125f;
        if (diag && (kt + kb * 16 + g * 4 + r > qg)) val = -1e30f;
        p[kb][r] = val;
        tmax = fmaxf(tmax, val);
      }
    tmax = fmaxf(tmax, __shfl_xor(tmax, 16));
    tmax = fmaxf(tmax, __shfl_xor(tmax, 32));
    float mnew = fmaxf(mst, tmax);
    float alpha = __expf(mst - mnew);
    float psum = 0.f;
    #pragma unroll
    for (int kb = 0; kb < 4; ++kb)
      #pragma unroll
      for (int r = 0; r < 4; ++r) {
        float e = __expf(p[kb][r] - mnew);
        p[kb][r] = e;
        psum += e;
      }
    psum += __shfl_xor(psum, 16);
    psum += __shfl_xor(psum, 32);
    lsum = lsum * alpha + psum;
    mst = mnew;
    #pragma unroll
    for (int db = 0; db < 4; ++db) {
      ot[db][0] *= alpha; ot[db][1] *= alpha;
      ot[db][2] *= alpha; ot[db][3] *= alpha;
    }

    #pragma unroll
    for (int h = 0; h < 2; ++h) {
      bfx8 pf;
      #pragma unroll
      for (int j = 0; j < 8; ++j)
        pf[j] = (__bf16)p[2 * h + (j >> 2)][j & 3];
      #pragma unroll
      for (int db = 0; db < 4; ++db) {
        us4 lo = *(const us4*)(&Vt[swz(16 * db + c, 32 * h + 4 * g)]);
        us4 hi = *(const us4*)(&Vt[swz(16 * db + c, 32 * h + 16 + 4 * g)]);
        union { us8 u; bfx8 bf; } cv;
        cv.u[0] = lo[0]; cv.u[1] = lo[1]; cv.u[2] = lo[2]; cv.u[3] = lo[3];
        cv.u[4] = hi[0]; cv.u[5] = hi[1]; cv.u[6] = hi[2]; cv.u[7] = hi[3];
        ot[db] = __builtin_amdgcn_mfma_f32_16x16x32_bf16(cv.bf, pf, ot[db], 0, 0, 0);
      }
    }
    __syncthreads();
  }

  if (q0 + c < kS) {
    float inv = 1.0f / lsum;
    u16* op = o + (size_t)(b * kS) * kD + hh * kDH + (size_t)(q0 + c) * kD;
    #pragma unroll
    for (int db = 0; db < 4; ++db)
      #pragma unroll
      for (int r = 0; r < 4; ++r)
        op[16 * db + 4 * g + r] = f2bf(ot[db][r] * inv);
  }
}

// ---------- gathers
__global__ void k_gather_obs(const u16* __restrict__ xf, u16* __restrict__ xo) {
  int r = blockIdx.x;
  int b = r / 960, rr = r % 960;
  int j = rr & 15, blk = rr >> 4;
  int s = blk * kTPB + j + (j == 15 ? 1 : 0);
  const unsigned int* src = (const unsigned int*)(xf + ((size_t)(b * kS + s)) * kD);
  unsigned int* dst = (unsigned int*)(xo + (size_t)r * kD);
  dst[threadIdx.x] = src[threadIdx.x];
  dst[threadIdx.x + 256] = src[threadIdx.x + 256];
}
__global__ void k_gather_act(const u16* __restrict__ xf, u16* __restrict__ xe) {
  int r = blockIdx.x;
  int b = r / 60, rr = r % 60;
  int s = rr * kTPB + (kTPB - 1);
  const unsigned int* src = (const unsigned int*)(xf + ((size_t)(b * kS + s)) * kD);
  unsigned int* dst = (unsigned int*)(xe + (size_t)r * kD);
  dst[threadIdx.x] = src[threadIdx.x];
  dst[threadIdx.x + 256] = src[threadIdx.x + 256];
}

// ---------- ends head (f32 out)
__global__ void k_ends(const u16* __restrict__ t2, const float* __restrict__ he2,
                       const float* __restrict__ be2, float* __restrict__ out) {
  int r = blockIdx.x;
  int t = threadIdx.x;
  float p0 = 0.f, p1 = 0.f;
  for (int j = t; j < kD; j += 256) {
    float xv = bf2f(t2[(size_t)r * kD + j]);
    p0 += xv * he2[j * 2];
    p1 += xv * he2[j * 2 + 1];
  }
  #pragma unroll
  for (int msk = 32; msk; msk >>= 1) { p0 += __shfl_xor(p0, msk); p1 += __shfl_xor(p1, msk); }
  __shared__ float l0[4], l1[4];
  int w = t >> 6;
  if ((t & 63) == 0) { l0[w] = p0; l1[w] = p1; }
  __syncthreads();
  if (t == 0) {
    out[r * 2 + 0] = l0[0] + l0[1] + l0[2] + l0[3] + be2[0];
    out[r * 2 + 1] = l1[0] + l1[1] + l1[2] + l1[3] + be2[1];
  }
}

} // namespace

extern "C" void kernel_launch(void* const* d_in, const int* in_sizes, int n_in,
                              void* d_out, int out_size, void* d_ws, size_t ws_size,
                              hipStream_t stream) {
  const int*   tokens  = (const int*)  d_in[0];
  const float* pos_emb = (const float*)d_in[1];
  const float* emb_obs = (const float*)d_in[2];
  const float* emb_act = (const float*)d_in[3];
  const float* ln1_g = (const float*)d_in[4];
  const float* ln1_b = (const float*)d_in[5];
  const float* wq = (const float*)d_in[6];
  const float* bq = (const float*)d_in[7];
  const float* wk = (const float*)d_in[8];
  const float* bk = (const float*)d_in[9];
  const float* wv = (const float*)d_in[10];
  const float* bv = (const float*)d_in[11];
  const float* wo = (const float*)d_in[12];
  const float* bo = (const float*)d_in[13];
  const float* ln2_g = (const float*)d_in[14];
  const float* ln2_b = (const float*)d_in[15];
  const float* w1 = (const float*)d_in[16];
  const float* b1 = (const float*)d_in[17];
  const float* w2 = (const float*)d_in[18];
  const float* b2 = (const float*)d_in[19];
  const float* lnf_g = (const float*)d_in[20];
  const float* lnf_b = (const float*)d_in[21];
  const float* ho1 = (const float*)d_in[22];
  const float* bo1 = (const float*)d_in[23];
  const float* ho2 = (const float*)d_in[24];
  const float* bo2 = (const float*)d_in[25];
  const float* he1 = (const float*)d_in[26];
  const float* be1 = (const float*)d_in[27];
  const float* he2 = (const float*)d_in[28];
  const float* be2 = (const float*)d_in[29];
  (void)in_sizes; (void)n_in; (void)out_size; (void)ws_size;

  // ---- workspace: ~74.9 MB
  char* ws = (char*)d_ws;
  size_t off = 0;
  auto alloc = [&](size_t bytes) -> char* {
    char* p = ws + off; off += (bytes + 255) & ~(size_t)255; return p;
  };
  u16*   wTbig = (u16*)alloc((size_t)4096 * 1024 * 2);    // 8 MB stacked B^T
  u16*   w2T   = (u16*)alloc((size_t)1024 * 4096 * 2);    // 8 MB w2^T / he1^T
  float* x  = (float*)alloc((size_t)kBS * kD * 4);        // 16.71 MB residual
  u16*   h  = (u16*)alloc((size_t)kBS * kD * 2);          // 8.36 MB LN out
  char*  scr = alloc((size_t)kBS * 4096 * 2);             // 33.42 MB
  float* bqkv = (float*)alloc((size_t)4 * 3072 * 4);      // 48 KB packed QKV bias
  const size_t slotB = (size_t)kBS * kD * 2;
  u16* qkv = (u16*)scr;                               // [4080][3072]
  u16* ob  = (u16*)(scr + (size_t)kBS * 3072 * 2);    // [4080][1024]
  u16* mid = (u16*)scr;                               // [4080][4096]
  u16* xf = (u16*)scr;
  u16* xo = (u16*)(scr + slotB);
  u16* t1 = (u16*)(scr + 2 * slotB);
  u16* xe = (u16*)(scr + 3 * slotB);
  u16* t2 = (u16*)(scr + 3 * slotB + (size_t)240 * kD * 2 + 256);

  dim3 tb(32, 8);
  dim3 tg(32, 32);
  k_embed<<<kBS, 256, 0, stream>>>(tokens, pos_emb, emb_obs, emb_act, x);
  k_pack_bias<<<48, 256, 0, stream>>>(bq, bk, bv, bqkv);

  const size_t MB1 = (size_t)1024 * 1024;
  for (int i = 0; i < 4; ++i) {
    const size_t wOff = (size_t)i * kD * kD;
    k_ln<<<kBS, 256, 0, stream>>>(x, ln1_g + i * kD, ln1_b + i * kD, h);

    // one batched transpose: wq,wk,wv -> wTbig rows 0..3071; wo -> rows 3072+
    {
      T4 sp{wq + wOff, wk + wOff, wv + wOff, wo + wOff,
            wTbig, wTbig + MB1, wTbig + 2 * MB1, wTbig + 3 * MB1, 1024};
      k_transpose4<<<dim3(32, 32, 4), tb, 0, stream>>>(sp);
    }
    k_gemm<0, 128><<<dim3(32, 24), 256, 0, stream>>>(h, wTbig, bqkv + i * 3072, nullptr, qkv,
                                                     kBS, 3072, 1024, 3072);

    k_attn<<<dim3(16, 64), 256, 0, stream>>>(qkv, qkv + 1024, qkv + 2048, ob, 3072);

    k_gemm<3, 64><<<dim3(64, 8), 256, 0, stream>>>(ob, wTbig + 3 * MB1, bo + i * kD, x, x,
                                                   kBS, 1024, 1024, 1024);

    k_ln<<<kBS, 256, 0, stream>>>(x, ln2_g + i * kD, ln2_b + i * kD, h);

    // FFN weights: w1 4 chunks -> wTbig, w2 -> w2T
    {
      const float* w1b = w1 + (size_t)i * kD * 4096;
      T4 sp{w1b, w1b + 1024, w1b + 2048, w1b + 3072,
            wTbig, wTbig + MB1, wTbig + 2 * MB1, wTbig + 3 * MB1, 4096};
      k_transpose4<<<dim3(32, 32, 4), tb, 0, stream>>>(sp);
    }
    k_transpose<<<dim3(32, 128), tb, 0, stream>>>(w2 + (size_t)i * 4096 * kD, w2T,
                                                  4096, 1024, 1024);
    k_gemm<2, 128><<<dim3(32, 32), 256, 0, stream>>>(h, wTbig, b1 + (size_t)i * 4096, nullptr,
                                                     mid, kBS, 4096, 1024, 4096);
    k_gemm<3, 64><<<dim3(64, 8), 256, 0, stream>>>(mid, w2T, b2 + i * kD, x, x,
                                                   kBS, 1024, 4096, 1024);
  }

  k_ln<<<kBS, 256, 0, stream>>>(x, lnf_g, lnf_b, xf);
  k_gather_obs<<<3840, 256, 0, stream>>>(xf, xo);
  k_gather_act<<<240, 256, 0, stream>>>(xf, xe);

  // obs head
  k_transpose<<<tg, tb, 0, stream>>>(ho1, wTbig, 1024, 1024, 1024);
  k_gemm<1, 64><<<dim3(60, 8), 256, 0, stream>>>(xo, wTbig, bo1, nullptr, t1,
                                                 3840, 1024, 1024, 1024);
  k_transpose<<<tg, tb, 0, stream>>>(he1, w2T, 1024, 1024, 1024);
  {
    T4 sp{ho2, ho2 + 1024, ho2 + 2048, ho2 + 3072,
          wTbig, wTbig + MB1, wTbig + 2 * MB1, wTbig + 3 * MB1, 4096};
    k_transpose4<<<dim3(32, 32, 4), tb, 0, stream>>>(sp);
  }
  k_gemm<4, 128><<<dim3(30, 32), 256, 0, stream>>>(t1, wTbig, bo2, nullptr,
                                                   (float*)d_out, 3840, 4096, 1024, 4096);
  // ends head
  k_gemm<1, 64><<<dim3(4, 8), 256, 0, stream>>>(xe, w2T, be1, nullptr, t2,
                                                240, 1024, 1024, 1024);
  k_ends<<<240, 256, 0, stream>>>(t2, he2, be2, (float*)d_out + (size_t)3840 * 4096);
}

// Round 11
// 1266.032 us; speedup vs baseline: 4.8361x; 1.0134x over previous
//
#include <hip/hip_runtime.h>
#include <hip/hip_bf16.h>
#include <math.h>

namespace {

constexpr int kS = 1020, kD = 1024, kTPB = 17, kDH = 64;
constexpr int kVOBS = 4096, kVACT = 16;
constexpr int kBS = 4080;          // B*S
constexpr float kEPS = 1e-3f;

typedef float f32x4 __attribute__((ext_vector_type(4)));
typedef __bf16 bfx8 __attribute__((ext_vector_type(8)));
typedef unsigned short u16;
typedef u16 us8 __attribute__((ext_vector_type(8)));
typedef u16 us4 __attribute__((ext_vector_type(4)));

__device__ __forceinline__ float bf2f(u16 u) {
  union { unsigned int i; float f; } v; v.i = (unsigned int)u << 16; return v.f;
}
__device__ __forceinline__ u16 f2bf(float f) {
  union { float f; unsigned int i; } v; v.f = f;
  unsigned int r = v.i + 0x7FFFu + ((v.i >> 16) & 1u);
  return (u16)(r >> 16);
}

// ---------- embed
__global__ void k_embed(const int* __restrict__ tokens, const float* __restrict__ pos_emb,
                        const float* __restrict__ emb_obs, const float* __restrict__ emb_act,
                        float* __restrict__ x) {
  int bs = blockIdx.x;
  int s = bs % kS;
  int tk = tokens[bs];
  bool obs = (s % kTPB) < (kTPB - 1);
  const float* e;
  if (obs) { int t2 = tk < kVOBS - 1 ? tk : kVOBS - 1; e = emb_obs + (size_t)t2 * kD; }
  else     { int t2 = tk < kVACT - 1 ? tk : kVACT - 1; e = emb_act + (size_t)t2 * kD; }
  int c = threadIdx.x * 4;
  float4 ev = *(const float4*)(e + c);
  float4 pv = *(const float4*)(pos_emb + (size_t)s * kD + c);
  float4 o; o.x = ev.x + pv.x; o.y = ev.y + pv.y; o.z = ev.z + pv.z; o.w = ev.w + pv.w;
  *(float4*)(x + (size_t)bs * kD + c) = o;
}

// ---------- bias pack (QKV)
__global__ void k_pack_bias(const float* __restrict__ bq, const float* __restrict__ bk,
                            const float* __restrict__ bv, float* __restrict__ bqkv) {
  int idx = blockIdx.x * 256 + threadIdx.x;      // 0..12287
  int l = idx / 3072, rem = idx % 3072;
  int sel = rem >> 10, cc = rem & 1023;
  const float* src = sel == 0 ? bq : (sel == 1 ? bk : bv);
  bqkv[idx] = src[l * kD + cc];
}

// ---------- LayerNorm: f32 in -> bf16 out.
__global__ void k_ln(const float* __restrict__ x, const float* __restrict__ g,
                     const float* __restrict__ b, u16* __restrict__ out) {
  int row = blockIdx.x;
  int t = threadIdx.x;
  const float* xr = x + (size_t)row * kD;
  float4 v = *(const float4*)(xr + t * 4);
  float s1 = v.x + v.y + v.z + v.w;
  float s2 = v.x * v.x + v.y * v.y + v.z * v.z + v.w * v.w;
  #pragma unroll
  for (int m = 32; m; m >>= 1) { s1 += __shfl_xor(s1, m); s2 += __shfl_xor(s2, m); }
  __shared__ float ls1[4], ls2[4];
  int w = t >> 6;
  if ((t & 63) == 0) { ls1[w] = s1; ls2[w] = s2; }
  __syncthreads();
  float S1 = ls1[0] + ls1[1] + ls1[2] + ls1[3];
  float S2 = ls2[0] + ls2[1] + ls2[2] + ls2[3];
  float mean = S1 * (1.0f / kD);
  float var = S2 * (1.0f / kD) - mean * mean;
  float rs = rsqrtf(var + kEPS);
  int c = t * 4;
  float4 gv = *(const float4*)(g + c);
  float4 bv = *(const float4*)(b + c);
  us4 o;
  o[0] = f2bf((v.x - mean) * rs * gv.x + bv.x);
  o[1] = f2bf((v.y - mean) * rs * gv.y + bv.y);
  o[2] = f2bf((v.z - mean) * rs * gv.z + bv.z);
  o[3] = f2bf((v.w - mean) * rs * gv.w + bv.w);
  *(us4*)(out + (size_t)row * kD + c) = o;
}

// ---------- transpose + f32->bf16 (single)
__global__ void k_transpose(const float* __restrict__ in, u16* __restrict__ out,
                            int R, int C, int ld) {
  __shared__ float tile[32][33];
  int tx = threadIdx.x, ty = threadIdx.y;
  int c0 = blockIdx.x * 32, r0 = blockIdx.y * 32;
  #pragma unroll
  for (int i = 0; i < 4; ++i)
    tile[ty + i * 8][tx] = in[(size_t)(r0 + ty + i * 8) * ld + c0 + tx];
  __syncthreads();
  #pragma unroll
  for (int i = 0; i < 4; ++i)
    out[(size_t)(c0 + ty + i * 8) * R + r0 + tx] = f2bf(tile[tx][ty + i * 8]);
}

// ---------- batched 1024x1024 transpose (4 segments via blockIdx.z)
struct T4 {
  const float* in0; const float* in1; const float* in2; const float* in3;
  u16* out0; u16* out1; u16* out2; u16* out3;
  int ld;
};
__global__ void k_transpose4(T4 sp) {
  const float* in; u16* out;
  switch (blockIdx.z) {
    case 0:  in = sp.in0; out = sp.out0; break;
    case 1:  in = sp.in1; out = sp.out1; break;
    case 2:  in = sp.in2; out = sp.out2; break;
    default: in = sp.in3; out = sp.out3; break;
  }
  __shared__ float tile[32][33];
  int tx = threadIdx.x, ty = threadIdx.y;
  int c0 = blockIdx.x * 32, r0 = blockIdx.y * 32;
  #pragma unroll
  for (int i = 0; i < 4; ++i)
    tile[ty + i * 8][tx] = in[(size_t)(r0 + ty + i * 8) * sp.ld + c0 + tx];
  __syncthreads();
  #pragma unroll
  for (int i = 0; i < 4; ++i)
    out[(size_t)(c0 + ty + i * 8) * 1024 + r0 + tx] = f2bf(tile[tx][ty + i * 8]);
}

// ---------- 256x256 8-phase GEMM (T2+T3+T4+T5 template, plain HIP).
// out[M][ldo] = A[M][K] * Bt[N][K]^T + bias. 512 thr = 8 waves (2M x 4N),
// wave output 128x64 (acc[8][4] f32x4). BK=64, 2-buffer LDS (128 KB).
// LDS: linear 128B rows; 16B-granule XOR swizzle g^=(row&7) on BOTH the
// global source (stage) and the ds_read side -> full-bandwidth reads.
// Per K-tile: 4 phases {ds_read || 2 gload_lds prefetch(t+1 -> buf^1) ->
// barrier -> lgkmcnt(0)+sched_barrier -> setprio(1) -> 16 MFMA -> setprio(0)
// -> barrier}; one vmcnt(0)+barrier per K-tile (loads fly >= 4 phases).
// Prefetch into buf[pb^1] is hazard-free: its previous tile's reads all
// completed before this tile's top barrier.
// EPI: 0 bf16, 2 bf16 gelu, 4 f32 store.
template <int EPI>
__global__ void __launch_bounds__(512, 2)
k_gemm256(const u16* __restrict__ A, const u16* __restrict__ Bt, const float* __restrict__ bias,
          void* __restrict__ out, int M, int K, int ldo) {
  __shared__ alignas(16) u16 As[2][256 * 64];
  __shared__ alignas(16) u16 Bs[2][256 * 64];
  const int tid = threadIdx.x;
  const int lane = tid & 63, wv = tid >> 6;
  const int wm = wv >> 2, wn = wv & 3;              // 2 x 4 waves
  const int m0 = blockIdx.x * 256, n0 = blockIdx.y * 256;
  f32x4 acc[8][4] = {};

  // stage iteration it: 0-3 stage A quarters, 4-7 stage B quarters.
  auto stageIter = [&](int buf, int k0, int it) {
    int u = (it & 3) * 512 + tid;                   // 0..2047
    int row = u >> 3, g = u & 7;
    int gsw = g ^ (row & 7);                        // pre-swizzled source granule
    int grow;
    const u16* srcBase;
    u16* dstBase;
    if (it < 4) {
      grow = m0 + row; if (grow >= M) grow = M - 1; // clamp: dup rows never stored
      srcBase = A; dstBase = &As[buf][0];
    } else {
      grow = n0 + row;                              // N multiple of 256 at all sites
      srcBase = Bt; dstBase = &Bs[buf][0];
    }
    const u16* src = srcBase + (size_t)grow * K + k0 + gsw * 8;
    u16* dst = dstBase + ((it & 3) * 512 + wv * 64) * 8;   // wave-uniform base
    __builtin_amdgcn_global_load_lds(
        (const __attribute__((address_space(1))) unsigned int*)src,
        (__attribute__((address_space(3))) unsigned int*)dst, 16, 0, 0);
  };

  const int nt = K >> 6;
  #pragma unroll
  for (int it = 0; it < 8; ++it) stageIter(0, 0, it);   // prologue: tile 0

  for (int t = 0; t < nt; ++t) {
    const int pb = t & 1;
    const int k0n = (t + 1) << 6;
    const bool pf = (t + 1 < nt);
    asm volatile("s_waitcnt vmcnt(0)" ::: "memory");    // tile t fully in LDS
    __builtin_amdgcn_s_barrier();
    __builtin_amdgcn_sched_barrier(0);

    #pragma unroll
    for (int kh = 0; kh < 2; ++kh) {
      bfx8 bfr[4], afr[4];
      // ---- phase (kh, rp=0): read B(kh) + A rows 0..63 of wave half
      #pragma unroll
      for (int n = 0; n < 4; ++n) {
        int row = wn * 64 + n * 16 + (lane & 15);
        bfr[n] = *(const bfx8*)(&Bs[pb][row * 64 + ((((kh << 2) + (lane >> 4)) ^ (row & 7)) << 3)]);
      }
      #pragma unroll
      for (int j = 0; j < 4; ++j) {
        int row = wm * 128 + j * 16 + (lane & 15);
        afr[j] = *(const bfx8*)(&As[pb][row * 64 + ((((kh << 2) + (lane >> 4)) ^ (row & 7)) << 3)]);
      }
      if (pf) { stageIter(pb ^ 1, k0n, kh * 4 + 0); stageIter(pb ^ 1, k0n, kh * 4 + 1); }
      __builtin_amdgcn_s_barrier();
      asm volatile("s_waitcnt lgkmcnt(0)" ::: "memory");
      __builtin_amdgcn_sched_barrier(0);               // rule 18: pin MFMA below wait
      __builtin_amdgcn_s_setprio(1);
      #pragma unroll
      for (int j = 0; j < 4; ++j)
        #pragma unroll
        for (int n = 0; n < 4; ++n)
          acc[j][n] = __builtin_amdgcn_mfma_f32_16x16x32_bf16(afr[j], bfr[n], acc[j][n], 0, 0, 0);
      __builtin_amdgcn_s_setprio(0);
      __builtin_amdgcn_s_barrier();

      // ---- phase (kh, rp=1): read A rows 64..127 of wave half (reuse bfr)
      #pragma unroll
      for (int j = 0; j < 4; ++j) {
        int row = wm * 128 + 64 + j * 16 + (lane & 15);
        afr[j] = *(const bfx8*)(&As[pb][row * 64 + ((((kh << 2) + (lane >> 4)) ^ (row & 7)) << 3)]);
      }
      if (pf) { stageIter(pb ^ 1, k0n, kh * 4 + 2); stageIter(pb ^ 1, k0n, kh * 4 + 3); }
      __builtin_amdgcn_s_barrier();
      asm volatile("s_waitcnt lgkmcnt(0)" ::: "memory");
      __builtin_amdgcn_sched_barrier(0);
      __builtin_amdgcn_s_setprio(1);
      #pragma unroll
      for (int j = 0; j < 4; ++j)
        #pragma unroll
        for (int n = 0; n < 4; ++n)
          acc[4 + j][n] = __builtin_amdgcn_mfma_f32_16x16x32_bf16(afr[j], bfr[n], acc[4 + j][n], 0, 0, 0);
      __builtin_amdgcn_s_setprio(0);
      __builtin_amdgcn_s_barrier();
    }
  }

  #pragma unroll
  for (int jf = 0; jf < 8; ++jf) {
    #pragma unroll
    for (int n = 0; n < 4; ++n) {
      int gcol = n0 + wn * 64 + n * 16 + (lane & 15);
      float bv = bias ? bias[gcol] : 0.0f;
      #pragma unroll
      for (int r = 0; r < 4; ++r) {
        int grow = m0 + wm * 128 + jf * 16 + (lane >> 4) * 4 + r;
        if (grow >= M) continue;
        float val = acc[jf][n][r] + bv;
        size_t o2 = (size_t)grow * ldo + gcol;
        if (EPI == 0) {
          ((u16*)out)[o2] = f2bf(val);
        } else if (EPI == 2) {
          ((u16*)out)[o2] = f2bf(0.5f * val * (1.f + erff(val * 0.70710678118654752440f)));
        } else {
          ((float*)out)[o2] = val;
        }
      }
    }
  }
}

// ---------- MFMA GEMM (N=1024 shapes): 3-buffer counted-vmcnt pipeline.
// EPI: 0 bf16, 1 bf16 relu, 2 bf16 gelu, 3 f32 resid+val, 4 f32 store
template <int EPI, int BM>
__global__ void __launch_bounds__(256)
k_gemm(const u16* __restrict__ A, const u16* __restrict__ Bt, const float* __restrict__ bias,
       const float* __restrict__ resid, void* __restrict__ out, int M, int N, int K, int ldo) {
  constexpr int MFRAG = BM / 32;
  constexpr int LOADS = BM / 64 + 2;
  __shared__ alignas(16) u16 As[3][BM * 32];
  __shared__ alignas(16) u16 Bs[3][128 * 32];
  int tid = threadIdx.x;
  int m0 = blockIdx.x * BM, n0 = blockIdx.y * 128;
  int lane = tid & 63, wv = tid >> 6;
  int wm = wv >> 1, wn = wv & 1;
  f32x4 acc[MFRAG][4] = {};

  auto stage = [&](int buf, int k0) {
    #pragma unroll
    for (int n = 0; n < BM / 64; ++n) {
      int u = n * 256 + tid;
      int r = u >> 2, ch = u & 3;
      int gr = m0 + r; if (gr >= M) gr = M - 1;
      int cg = ch ^ ((r >> 1) & 3);
      const u16* src = A + (size_t)gr * K + k0 + cg * 8;
      __builtin_amdgcn_global_load_lds(
          (const __attribute__((address_space(1))) unsigned int*)src,
          (__attribute__((address_space(3))) unsigned int*)&As[buf][(n * 256 + wv * 64) * 8],
          16, 0, 0);
    }
    #pragma unroll
    for (int n = 0; n < 2; ++n) {
      int u = n * 256 + tid;
      int r = u >> 2, ch = u & 3;
      int cg = ch ^ ((r >> 1) & 3);
      const u16* src = Bt + (size_t)(n0 + r) * K + k0 + cg * 8;
      __builtin_amdgcn_global_load_lds(
          (const __attribute__((address_space(1))) unsigned int*)src,
          (__attribute__((address_space(3))) unsigned int*)&Bs[buf][(n * 256 + wv * 64) * 8],
          16, 0, 0);
    }
  };

  const int nk = K >> 5;
  stage(0, 0);
  stage(1, 32);
  stage(2, 64);
  for (int t = 0; t < nk; ++t) {
    int cur = t % 3;
    if (t + 2 < nk)
      asm volatile("s_waitcnt vmcnt(%0)" :: "i"(2 * LOADS) : "memory");
    else if (t + 1 < nk)
      asm volatile("s_waitcnt vmcnt(%0)" :: "i"(LOADS) : "memory");
    else
      asm volatile("s_waitcnt vmcnt(0)" ::: "memory");
    __builtin_amdgcn_s_barrier();
    __builtin_amdgcn_sched_barrier(0);

    bfx8 af[MFRAG], bfr[4];
    int ch = lane >> 4;
    #pragma unroll
    for (int mf = 0; mf < MFRAG; ++mf) {
      int row = wm * (BM / 2) + mf * 16 + (lane & 15);
      af[mf] = *(const bfx8*)(&As[cur][row * 32 + ((ch ^ ((row >> 1) & 3)) << 3)]);
    }
    #pragma unroll
    for (int nf = 0; nf < 4; ++nf) {
      int row = wn * 64 + nf * 16 + (lane & 15);
      bfr[nf] = *(const bfx8*)(&Bs[cur][row * 32 + ((ch ^ ((row >> 1) & 3)) << 3)]);
    }
    asm volatile("s_waitcnt lgkmcnt(0)" ::: "memory");
    __builtin_amdgcn_s_barrier();
    __builtin_amdgcn_sched_barrier(0);
    if (t + 3 < nk) stage(cur, (t + 3) << 5);

    #pragma unroll
    for (int mf = 0; mf < MFRAG; ++mf)
      #pragma unroll
      for (int nf = 0; nf < 4; ++nf)
        acc[mf][nf] = __builtin_amdgcn_mfma_f32_16x16x32_bf16(af[mf], bfr[nf], acc[mf][nf], 0, 0, 0);
  }

  #pragma unroll
  for (int mf = 0; mf < MFRAG; ++mf) {
    #pragma unroll
    for (int nf = 0; nf < 4; ++nf) {
      int gcol = n0 + wn * 64 + nf * 16 + (lane & 15);
      float bv = bias ? bias[gcol] : 0.0f;
      #pragma unroll
      for (int r = 0; r < 4; ++r) {
        int grow = m0 + wm * (BM / 2) + mf * 16 + (lane >> 4) * 4 + r;
        if (grow >= M) continue;
        float val = acc[mf][nf][r] + bv;
        size_t off2 = (size_t)grow * ldo + gcol;
        if (EPI == 0) {
          ((u16*)out)[off2] = f2bf(val);
        } else if (EPI == 1) {
          ((u16*)out)[off2] = f2bf(val > 0.f ? val : 0.f);
        } else if (EPI == 2) {
          ((u16*)out)[off2] = f2bf(0.5f * val * (1.f + erff(val * 0.70710678118654752440f)));
        } else if (EPI == 3) {
          ((float*)out)[off2] = resid[off2] + val;
        } else {
          ((float*)out)[off2] = val;
        }
      }
    }
  }
}

// ---------- MFMA flash attention (swapped-operand). q/k/v row stride = ldin.
__device__ __forceinline__ int swz(int row, int colu16) {
  return (row * 64 + colu16) ^ ((row & 7) << 3) ^ ((row & 24) << 1);
}

__global__ void __launch_bounds__(256)
k_attn(const u16* __restrict__ q, const u16* __restrict__ k, const u16* __restrict__ v,
       u16* __restrict__ o, int ldin) {
  __shared__ u16 Kl[64 * 64];
  __shared__ u16 Vt[64 * 64];
  const int qb = blockIdx.x * 64;
  const int bh = blockIdx.y;
  const int b = bh >> 4, hh = bh & 15;
  const int tid = threadIdx.x;
  const int lane = tid & 63, w = tid >> 6;
  const int g = lane >> 4, c = lane & 15;
  const int q0 = qb + w * 16;
  const size_t base = (size_t)(b * kS) * ldin + hh * kDH;

  bfx8 qf0, qf1;
  {
    int qr = q0 + c; if (qr >= kS) qr = kS - 1;
    const u16* qp = q + base + (size_t)qr * ldin + g * 8;
    qf0 = *(const bfx8*)(qp);
    qf1 = *(const bfx8*)(qp + 32);
  }

  float mst = -1e30f, lsum = 0.f;
  f32x4 ot[4] = {};

  const int ntiles = blockIdx.x + 1;
  for (int t = 0; t < ntiles; ++t) {
    const int kt = t * 64;
    {
      int kr = tid >> 2, ds2 = (tid & 3) * 16;
      int kg = kt + kr; if (kg >= kS) kg = kS - 1;
      const u16* kp = k + base + (size_t)kg * ldin + ds2;
      us8 a0 = *(const us8*)(kp);
      us8 a1 = *(const us8*)(kp + 8);
      *(us8*)(&Kl[swz(kr, ds2)]) = a0;
      *(us8*)(&Kl[swz(kr, ds2 + 8)]) = a1;
      const u16* vp = v + base + (size_t)kg * ldin + ds2;
      us8 b0 = *(const us8*)(vp);
      us8 b1 = *(const us8*)(vp + 8);
      #pragma unroll
      for (int i2 = 0; i2 < 8; ++i2) Vt[swz(ds2 + i2, kr)] = b0[i2];
      #pragma unroll
      for (int i2 = 0; i2 < 8; ++i2) Vt[swz(ds2 + 8 + i2, kr)] = b1[i2];
    }
    __syncthreads();

    f32x4 s[4];
    #pragma unroll
    for (int kb = 0; kb < 4; ++kb) {
      bfx8 kf0 = *(const bfx8*)(&Kl[swz(kb * 16 + c, g * 8)]);
      bfx8 kf1 = *(const bfx8*)(&Kl[swz(kb * 16 + c, g * 8 + 32)]);
      f32x4 acc = {};
      acc = __builtin_amdgcn_mfma_f32_16x16x32_bf16(kf0, qf0, acc, 0, 0, 0);
      acc = __builtin_amdgcn_mfma_f32_16x16x32_bf16(kf1, qf1, acc, 0, 0, 0);
      s[kb] = acc;
    }

    const int qg = q0 + c;
    const bool diag = (kt + 63 > q0);
    float p[4][4];
    float tmax = -1e30f;
    #pragma unroll
    for (int kb = 0; kb < 4; ++kb)
      #pragma unroll
      for (int r = 0; r < 4; ++r) {
        float val = s[kb][r] * 0.125f;
        if (diag && (kt + kb * 16 + g * 4 + r > qg)) val = -1e30f;
        p[kb][r] = val;
        tmax = fmaxf(tmax, val);
      }
    tmax = fmaxf(tmax, __shfl_xor(tmax, 16));
    tmax = fmaxf(tmax, __shfl_xor(tmax, 32));
    float mnew = fmaxf(mst, tmax);
    float alpha = __expf(mst - mnew);
    float psum = 0.f;
    #pragma unroll
    for (int kb = 0; kb < 4; ++kb)
      #pragma unroll
      for (int r = 0; r < 4; ++r) {
        float e = __expf(p[kb][r] - mnew);
        p[kb][r] = e;
        psum += e;
      }
    psum += __shfl_xor(psum, 16);
    psum += __shfl_xor(psum, 32);
    lsum = lsum * alpha + psum;
    mst = mnew;
    #pragma unroll
    for (int db = 0; db < 4; ++db) {
      ot[db][0] *= alpha; ot[db][1] *= alpha;
      ot[db][2] *= alpha; ot[db][3] *= alpha;
    }

    #pragma unroll
    for (int h = 0; h < 2; ++h) {
      bfx8 pf;
      #pragma unroll
      for (int j = 0; j < 8; ++j)
        pf[j] = (__bf16)p[2 * h + (j >> 2)][j & 3];
      #pragma unroll
      for (int db = 0; db < 4; ++db) {
        us4 lo = *(const us4*)(&Vt[swz(16 * db + c, 32 * h + 4 * g)]);
        us4 hi = *(const us4*)(&Vt[swz(16 * db + c, 32 * h + 16 + 4 * g)]);
        union { us8 u; bfx8 bf; } cv;
        cv.u[0] = lo[0]; cv.u[1] = lo[1]; cv.u[2] = lo[2]; cv.u[3] = lo[3];
        cv.u[4] = hi[0]; cv.u[5] = hi[1]; cv.u[6] = hi[2]; cv.u[7] = hi[3];
        ot[db] = __builtin_amdgcn_mfma_f32_16x16x32_bf16(cv.bf, pf, ot[db], 0, 0, 0);
      }
    }
    __syncthreads();
  }

  if (q0 + c < kS) {
    float inv = 1.0f / lsum;
    u16* op = o + (size_t)(b * kS) * kD + hh * kDH + (size_t)(q0 + c) * kD;
    #pragma unroll
    for (int db = 0; db < 4; ++db)
      #pragma unroll
      for (int r = 0; r < 4; ++r)
        op[16 * db + 4 * g + r] = f2bf(ot[db][r] * inv);
  }
}

// ---------- gathers
__global__ void k_gather_obs(const u16* __restrict__ xf, u16* __restrict__ xo) {
  int r = blockIdx.x;
  int b = r / 960, rr = r % 960;
  int j = rr & 15, blk = rr >> 4;
  int s = blk * kTPB + j + (j == 15 ? 1 : 0);
  const unsigned int* src = (const unsigned int*)(xf + ((size_t)(b * kS + s)) * kD);
  unsigned int* dst = (unsigned int*)(xo + (size_t)r * kD);
  dst[threadIdx.x] = src[threadIdx.x];
  dst[threadIdx.x + 256] = src[threadIdx.x + 256];
}
__global__ void k_gather_act(const u16* __restrict__ xf, u16* __restrict__ xe) {
  int r = blockIdx.x;
  int b = r / 60, rr = r % 60;
  int s = rr * kTPB + (kTPB - 1);
  const unsigned int* src = (const unsigned int*)(xf + ((size_t)(b * kS + s)) * kD);
  unsigned int* dst = (unsigned int*)(xe + (size_t)r * kD);
  dst[threadIdx.x] = src[threadIdx.x];
  dst[threadIdx.x + 256] = src[threadIdx.x + 256];
}

// ---------- ends head (f32 out)
__global__ void k_ends(const u16* __restrict__ t2, const float* __restrict__ he2,
                       const float* __restrict__ be2, float* __restrict__ out) {
  int r = blockIdx.x;
  int t = threadIdx.x;
  float p0 = 0.f, p1 = 0.f;
  for (int j = t; j < kD; j += 256) {
    float xv = bf2f(t2[(size_t)r * kD + j]);
    p0 += xv * he2[j * 2];
    p1 += xv * he2[j * 2 + 1];
  }
  #pragma unroll
  for (int msk = 32; msk; msk >>= 1) { p0 += __shfl_xor(p0, msk); p1 += __shfl_xor(p1, msk); }
  __shared__ float l0[4], l1[4];
  int w = t >> 6;
  if ((t & 63) == 0) { l0[w] = p0; l1[w] = p1; }
  __syncthreads();
  if (t == 0) {
    out[r * 2 + 0] = l0[0] + l0[1] + l0[2] + l0[3] + be2[0];
    out[r * 2 + 1] = l1[0] + l1[1] + l1[2] + l1[3] + be2[1];
  }
}

} // namespace

extern "C" void kernel_launch(void* const* d_in, const int* in_sizes, int n_in,
                              void* d_out, int out_size, void* d_ws, size_t ws_size,
                              hipStream_t stream) {
  const int*   tokens  = (const int*)  d_in[0];
  const float* pos_emb = (const float*)d_in[1];
  const float* emb_obs = (const float*)d_in[2];
  const float* emb_act = (const float*)d_in[3];
  const float* ln1_g = (const float*)d_in[4];
  const float* ln1_b = (const float*)d_in[5];
  const float* wq = (const float*)d_in[6];
  const float* bq = (const float*)d_in[7];
  const float* wk = (const float*)d_in[8];
  const float* bk = (const float*)d_in[9];
  const float* wv = (const float*)d_in[10];
  const float* bv = (const float*)d_in[11];
  const float* wo = (const float*)d_in[12];
  const float* bo = (const float*)d_in[13];
  const float* ln2_g = (const float*)d_in[14];
  const float* ln2_b = (const float*)d_in[15];
  const float* w1 = (const float*)d_in[16];
  const float* b1 = (const float*)d_in[17];
  const float* w2 = (const float*)d_in[18];
  const float* b2 = (const float*)d_in[19];
  const float* lnf_g = (const float*)d_in[20];
  const float* lnf_b = (const float*)d_in[21];
  const float* ho1 = (const float*)d_in[22];
  const float* bo1 = (const float*)d_in[23];
  const float* ho2 = (const float*)d_in[24];
  const float* bo2 = (const float*)d_in[25];
  const float* he1 = (const float*)d_in[26];
  const float* be1 = (const float*)d_in[27];
  const float* he2 = (const float*)d_in[28];
  const float* be2 = (const float*)d_in[29];
  (void)in_sizes; (void)n_in; (void)out_size; (void)ws_size;

  // ---- workspace: ~74.9 MB
  char* ws = (char*)d_ws;
  size_t off = 0;
  auto alloc = [&](size_t bytes) -> char* {
    char* p = ws + off; off += (bytes + 255) & ~(size_t)255; return p;
  };
  u16*   wTbig = (u16*)alloc((size_t)4096 * 1024 * 2);    // 8 MB stacked B^T
  u16*   w2T   = (u16*)alloc((size_t)1024 * 4096 * 2);    // 8 MB w2^T / he1^T
  float* x  = (float*)alloc((size_t)kBS * kD * 4);        // 16.71 MB residual
  u16*   h  = (u16*)alloc((size_t)kBS * kD * 2);          // 8.36 MB LN out
  char*  scr = alloc((size_t)kBS * 4096 * 2);             // 33.42 MB
  float* bqkv = (float*)alloc((size_t)4 * 3072 * 4);      // 48 KB packed QKV bias
  const size_t slotB = (size_t)kBS * kD * 2;
  u16* qkv = (u16*)scr;                               // [4080][3072]
  u16* ob  = (u16*)(scr + (size_t)kBS * 3072 * 2);    // [4080][1024]
  u16* mid = (u16*)scr;                               // [4080][4096]
  u16* xf = (u16*)scr;
  u16* xo = (u16*)(scr + slotB);
  u16* t1 = (u16*)(scr + 2 * slotB);
  u16* xe = (u16*)(scr + 3 * slotB);
  u16* t2 = (u16*)(scr + 3 * slotB + (size_t)240 * kD * 2 + 256);

  dim3 tb(32, 8);
  dim3 tg(32, 32);
  k_embed<<<kBS, 256, 0, stream>>>(tokens, pos_emb, emb_obs, emb_act, x);
  k_pack_bias<<<48, 256, 0, stream>>>(bq, bk, bv, bqkv);

  const size_t MB1 = (size_t)1024 * 1024;
  for (int i = 0; i < 4; ++i) {
    const size_t wOff = (size_t)i * kD * kD;
    k_ln<<<kBS, 256, 0, stream>>>(x, ln1_g + i * kD, ln1_b + i * kD, h);

    {
      T4 sp{wq + wOff, wk + wOff, wv + wOff, wo + wOff,
            wTbig, wTbig + MB1, wTbig + 2 * MB1, wTbig + 3 * MB1, 1024};
      k_transpose4<<<dim3(32, 32, 4), tb, 0, stream>>>(sp);
    }
    k_gemm256<0><<<dim3(16, 12), 512, 0, stream>>>(h, wTbig, bqkv + i * 3072, qkv,
                                                   kBS, 1024, 3072);

    k_attn<<<dim3(16, 64), 256, 0, stream>>>(qkv, qkv + 1024, qkv + 2048, ob, 3072);

    k_gemm<3, 64><<<dim3(64, 8), 256, 0, stream>>>(ob, wTbig + 3 * MB1, bo + i * kD, x, x,
                                                   kBS, 1024, 1024, 1024);

    k_ln<<<kBS, 256, 0, stream>>>(x, ln2_g + i * kD, ln2_b + i * kD, h);

    {
      const float* w1b = w1 + (size_t)i * kD * 4096;
      T4 sp{w1b, w1b + 1024, w1b + 2048, w1b + 3072,
            wTbig, wTbig + MB1, wTbig + 2 * MB1, wTbig + 3 * MB1, 4096};
      k_transpose4<<<dim3(32, 32, 4), tb, 0, stream>>>(sp);
    }
    k_transpose<<<dim3(32, 128), tb, 0, stream>>>(w2 + (size_t)i * 4096 * kD, w2T,
                                                  4096, 1024, 1024);
    k_gemm256<2><<<dim3(16, 16), 512, 0, stream>>>(h, wTbig, b1 + (size_t)i * 4096,
                                                   mid, kBS, 1024, 4096);
    k_gemm<3, 64><<<dim3(64, 8), 256, 0, stream>>>(mid, w2T, b2 + i * kD, x, x,
                                                   kBS, 1024, 4096, 1024);
  }

  k_ln<<<kBS, 256, 0, stream>>>(x, lnf_g, lnf_b, xf);
  k_gather_obs<<<3840, 256, 0, stream>>>(xf, xo);
  k_gather_act<<<240, 256, 0, stream>>>(xf, xe);

  // obs head
  k_transpose<<<tg, tb, 0, stream>>>(ho1, wTbig, 1024, 1024, 1024);
  k_gemm<1, 64><<<dim3(60, 8), 256, 0, stream>>>(xo, wTbig, bo1, nullptr, t1,
                                                 3840, 1024, 1024, 1024);
  k_transpose<<<tg, tb, 0, stream>>>(he1, w2T, 1024, 1024, 1024);
  {
    T4 sp{ho2, ho2 + 1024, ho2 + 2048, ho2 + 3072,
          wTbig, wTbig + MB1, wTbig + 2 * MB1, wTbig + 3 * MB1, 4096};
    k_transpose4<<<dim3(32, 32, 4), tb, 0, stream>>>(sp);
  }
  k_gemm256<4><<<dim3(15, 16), 512, 0, stream>>>(t1, wTbig, bo2,
                                                 (float*)d_out, 3840, 1024, 4096);
  // ends head
  k_gemm<1, 64><<<dim3(4, 8), 256, 0, stream>>>(xe, w2T, be1, nullptr, t2,
                                                240, 1024, 1024, 1024);
  k_ends<<<240, 256, 0, stream>>>(t2, he2, be2, (float*)d_out + (size_t)3840 * 4096);
}